// Round 3
// baseline (224.208 us; speedup 1.0000x reference)
//
#include <hip/hip_runtime.h>
#include <cstdint>
#include <cstddef>

#define DEVI __device__ __forceinline__

typedef __bf16 bf16_t;
typedef __bf16 bf16x4 __attribute__((ext_vector_type(4)));
typedef __bf16 bf16x8 __attribute__((ext_vector_type(8)));
typedef float  f32x4  __attribute__((ext_vector_type(4)));
typedef float  f32x16 __attribute__((ext_vector_type(16)));
typedef unsigned short u16x4 __attribute__((ext_vector_type(4)));
typedef unsigned int   u32x4 __attribute__((ext_vector_type(4)));

static constexpr int Bz = 2, S = 2048, E = 1024, H = 16, Dh = 64;
static constexpr int M  = Bz * S;   // 4096 tokens
static constexpr int N  = H * Dh;   // 1024
static constexpr int Kd = E;        // 1024

DEVI unsigned short f2bf(float f) {
  unsigned u = __builtin_bit_cast(unsigned, f);
  return (unsigned short)((u + 0x7fffu + ((u >> 16) & 1u)) >> 16);
}

DEVI void async_copy16(void* lds, const void* g) {
  __builtin_amdgcn_global_load_lds((__attribute__((address_space(1))) void*)(g),
                                   (__attribute__((address_space(3))) void*)(lds), 16, 0, 0);
}

DEVI void block_sync() { asm volatile("s_barrier" ::: "memory"); }
#define VMCNT4() asm volatile("s_waitcnt vmcnt(4)" ::: "memory")
#define VMCNT0() asm volatile("s_waitcnt vmcnt(0)" ::: "memory")

// pack two f32 -> dword of two bf16 (RNE)
DEVI unsigned cvtpk(float lo, float hi) {
  unsigned r;
  asm("v_cvt_pk_bf16_f32 %0, %1, %2" : "=v"(r) : "v"(lo), "v"(hi));
  return r;
}
// swap x's lanes 32-63 with y's lanes 0-31
DEVI void swap32(unsigned& x, unsigned& y) {
  asm("v_permlane32_swap_b32 %0, %1" : "+v"(x), "+v"(y));
}

// ---------------- fused prep: convx | wtrans | rope table ----------------
__global__ void prep_kernel(const float* __restrict__ x, bf16_t* __restrict__ xb,
                            const float* __restrict__ Wq, const float* __restrict__ Wk,
                            const float* __restrict__ Wv, const float* __restrict__ Wo,
                            bf16_t* __restrict__ WtBase,
                            float* __restrict__ ropeC, float* __restrict__ ropeS) {
  __shared__ unsigned short tile[64][68];
  const int blk = blockIdx.x, tid = threadIdx.x;
  if (blk < 4096) {
    // x fp32 -> bf16
    int i = blk * 256 + tid;
    float4 v = ((const float4*)x)[i];
    u16x4 o = { f2bf(v.x), f2bf(v.y), f2bf(v.z), f2bf(v.w) };
    ((u16x4*)xb)[i] = o;
  } else if (blk < 5120) {
    // weight fp32 [K][N] -> bf16 [N][K]
    const int i = blk - 4096;
    const int z = i >> 8, rest = i & 255;
    const int n0 = (rest & 15) * 64, k0 = (rest >> 4) * 64;
    const float* W = (z == 0) ? Wq : (z == 1) ? Wk : (z == 2) ? Wv : Wo;
    unsigned short* T = (unsigned short*)(WtBase + (size_t)z * Kd * N);
    for (int e = tid; e < 1024; e += 256) {
      int r = e >> 4, c4 = (e & 15) * 4;
      float4 v = *(const float4*)(W + (size_t)(k0 + r) * N + n0 + c4);
      u16x4 o = { f2bf(v.x), f2bf(v.y), f2bf(v.z), f2bf(v.w) };
      *(u16x4*)&tile[r][c4] = o;
    }
    __syncthreads();
    for (int e = tid; e < 1024; e += 256) {
      int r = e >> 4, c4 = (e & 15) * 4;
      u16x4 o = { tile[c4][r], tile[c4 + 1][r], tile[c4 + 2][r], tile[c4 + 3][r] };
      *(u16x4*)&T[(size_t)(n0 + r) * Kd + k0 + c4] = o;
    }
  } else {
    int i = (blk - 5120) * 256 + tid;            // 65536 = 2048*32
    int pos = i >> 5, j = i & 31;
    float inv = exp2f(-(float)j * 0.41524101186092029f);   // log2(10000)/32
    float ang = (float)pos * inv;
    ropeC[i] = cosf(ang);
    ropeS[i] = sinf(ang);
  }
}

// bf16 [BH][S][D] -> bf16 [BH][D][S]
__global__ void vtrans_kernel(const bf16_t* __restrict__ V, bf16_t* __restrict__ Vt) {
  __shared__ unsigned short tile[64][68];
  const int bh = blockIdx.y;
  const int s0 = blockIdx.x * 64;
  const unsigned short* Vp = (const unsigned short*)V + (size_t)bh * S * Dh;
  unsigned short* Tp = (unsigned short*)Vt + (size_t)bh * Dh * S;
  const int tid = threadIdx.x;
  for (int e = tid; e < 1024; e += 256) {
    int r = e >> 4, c4 = (e & 15) * 4;
    u16x4 v = *(const u16x4*)(Vp + (size_t)(s0 + r) * Dh + c4);
    *(u16x4*)&tile[r][c4] = v;
  }
  __syncthreads();
  for (int e = tid; e < 1024; e += 256) {
    int d = e >> 4, s4 = (e & 15) * 4;
    u16x4 o = { tile[s4][d], tile[s4 + 1][d], tile[s4 + 2][d], tile[s4 + 3][d] };
    *(u16x4*)&Tp[(size_t)d * S + s0 + s4] = o;
  }
}

// ---------------- GEMM core (128x128 tile, BK=32, global_load_lds) ----------------

DEVI void gemm_mainloop(const bf16_t* __restrict__ A, const bf16_t* __restrict__ Bt,
                        bf16_t* sA, bf16_t* sB, int m0, int n0, f32x4 (&acc)[4][4]) {
  const int tid  = threadIdx.x;
  const int lane = tid & 63;
  const int wid  = tid >> 6;
  const int l16  = lane & 15;
  const int quad = lane >> 4;
  const int wm = (wid >> 1) * 64;
  const int wn = (wid & 1) * 64;
  const int o0 = wid * 2048 + lane * 16;   // byte offset within 8KB tile
  const int o1 = o0 + 1024;
  const int r0 = o0 >> 6, c0 = o0 & 63;
  const int r1 = o1 >> 6, c1 = o1 & 63;
  const char* Ab = (const char*)A;
  const char* Bb = (const char*)Bt;
  char* sAc = (char*)sA;
  char* sBc = (char*)sB;

  for (int k0 = 0; k0 < Kd; k0 += 32) {
    __syncthreads();
    async_copy16(sAc + wid * 2048,        Ab + ((size_t)(m0 + r0) * Kd + k0) * 2 + c0);
    async_copy16(sAc + wid * 2048 + 1024, Ab + ((size_t)(m0 + r1) * Kd + k0) * 2 + c1);
    async_copy16(sBc + wid * 2048,        Bb + ((size_t)(n0 + r0) * Kd + k0) * 2 + c0);
    async_copy16(sBc + wid * 2048 + 1024, Bb + ((size_t)(n0 + r1) * Kd + k0) * 2 + c1);
    __syncthreads();
    bf16x8 af[4], bfv[4];
#pragma unroll
    for (int mi = 0; mi < 4; ++mi)
      af[mi] = *(const bf16x8*)(sA + (wm + mi * 16 + l16) * 32 + quad * 8);
#pragma unroll
    for (int ni = 0; ni < 4; ++ni)
      bfv[ni] = *(const bf16x8*)(sB + (wn + ni * 16 + l16) * 32 + quad * 8);
#pragma unroll
    for (int mi = 0; mi < 4; ++mi)
#pragma unroll
      for (int ni = 0; ni < 4; ++ni)
        acc[mi][ni] = __builtin_amdgcn_mfma_f32_16x16x32_bf16(af[mi], bfv[ni], acc[mi][ni], 0, 0, 0);
  }
}

// z = 0:Q(RoPE+scale) 1:K(RoPE) 2:V ; out layout [B,H,S,D] bf16
__global__ __launch_bounds__(256, 3) void gemm_qkv_kernel(
    const bf16_t* __restrict__ xb, const bf16_t* __restrict__ WtBase,
    const float* __restrict__ bq, const float* __restrict__ bk, const float* __restrict__ bv,
    bf16_t* __restrict__ outBase,
    const float* __restrict__ ropeC, const float* __restrict__ ropeS) {
  __shared__ bf16_t sA[4096], sB[4096];
  const int z = blockIdx.z;
  const bf16_t* Bt = WtBase + (size_t)z * Kd * N;
  const float* bias = (z == 0) ? bq : (z == 1) ? bk : bv;
  unsigned short* outp = (unsigned short*)(outBase + (size_t)z * M * N);
  const int n0 = blockIdx.x * 128, m0 = blockIdx.y * 128;
  f32x4 acc[4][4] = {};
  gemm_mainloop(xb, Bt, sA, sB, m0, n0, acc);

  const int tid = threadIdx.x, lane = tid & 63, wid = tid >> 6;
  const int l16 = lane & 15, quad = lane >> 4;
  const int wm = (wid >> 1) * 64, wn = (wid & 1) * 64;
  const int cbase = n0 + wn;          // 64-aligned -> one head per wave slab
  const int h = cbase >> 6;

  if (z < 2) {
    // Q gets 0.125 (=1/sqrt(D)) * log2(e) folded in so attention can use exp2
    const float qs = (z == 0) ? 0.18033688011112042f : 1.0f;
#pragma unroll
    for (int mi = 0; mi < 4; ++mi)
#pragma unroll
      for (int r = 0; r < 4; ++r) {
        int t = m0 + wm + mi * 16 + quad * 4 + r;
        int bb = t >> 11, s = t & (S - 1);
        size_t obase = ((size_t)(bb * H + h) * S + s) * Dh;
#pragma unroll
        for (int np = 0; np < 2; ++np) {
          int j = np * 16 + l16;                 // = d (low half), d-32 (high half)
          float cc = ropeC[s * 32 + j];
          float ss = ropeS[s * 32 + j];
          float xlo = acc[mi][np][r]     + bias[cbase + j];
          float xhi = acc[mi][np + 2][r] + bias[cbase + j + 32];
          outp[obase + j]      = f2bf((xlo * cc - xhi * ss) * qs);
          outp[obase + j + 32] = f2bf((xhi * cc + xlo * ss) * qs);
        }
      }
  } else {
#pragma unroll
    for (int mi = 0; mi < 4; ++mi)
#pragma unroll
      for (int r = 0; r < 4; ++r) {
        int t = m0 + wm + mi * 16 + quad * 4 + r;
        int bb = t >> 11, s = t & (S - 1);
        size_t obase = ((size_t)(bb * H + h) * S + s) * Dh;
#pragma unroll
        for (int ni = 0; ni < 4; ++ni) {
          int d = ni * 16 + l16;
          outp[obase + d] = f2bf(acc[mi][ni][r] + bias[cbase + d]);
        }
      }
  }
}

// output GEMM: 64(m) x 128(n) tiles -> 512 blocks (2/CU)
__global__ __launch_bounds__(256, 4) void gemm_o_kernel(
    const bf16_t* __restrict__ A, const bf16_t* __restrict__ Bt,
    const float* __restrict__ bias, float* __restrict__ out) {
  __shared__ bf16_t sA[2048], sB[4096];     // 4KB A (64x32), 8KB B (128x32)
  const int n0 = blockIdx.x * 128, m0 = blockIdx.y * 64;
  const int tid = threadIdx.x, lane = tid & 63, wid = tid >> 6;
  const int l16 = lane & 15, quad = lane >> 4;
  const int wm = (wid >> 1) * 32, wn = (wid & 1) * 64;
  const int rowoff = lane >> 2, col8 = (lane & 3) * 8;
  const char* Ab = (const char*)A;
  const char* Bb = (const char*)Bt;
  char* sAc = (char*)sA;
  char* sBc = (char*)sB;
  f32x4 acc[2][4] = {};

  for (int k0 = 0; k0 < Kd; k0 += 32) {
    __syncthreads();
    async_copy16(sAc + wid * 1024,
                 Ab + ((size_t)(m0 + wid * 16 + rowoff) * Kd + k0 + col8) * 2);
    async_copy16(sBc + (wid * 2) * 1024,
                 Bb + ((size_t)(n0 + wid * 32 + rowoff) * Kd + k0 + col8) * 2);
    async_copy16(sBc + (wid * 2 + 1) * 1024,
                 Bb + ((size_t)(n0 + wid * 32 + 16 + rowoff) * Kd + k0 + col8) * 2);
    __syncthreads();
    bf16x8 af[2], bfv[4];
#pragma unroll
    for (int mi = 0; mi < 2; ++mi)
      af[mi] = *(const bf16x8*)(sA + (wm + mi * 16 + l16) * 32 + quad * 8);
#pragma unroll
    for (int ni = 0; ni < 4; ++ni)
      bfv[ni] = *(const bf16x8*)(sB + (wn + ni * 16 + l16) * 32 + quad * 8);
#pragma unroll
    for (int mi = 0; mi < 2; ++mi)
#pragma unroll
      for (int ni = 0; ni < 4; ++ni)
        acc[mi][ni] = __builtin_amdgcn_mfma_f32_16x16x32_bf16(af[mi], bfv[ni], acc[mi][ni], 0, 0, 0);
  }
#pragma unroll
  for (int mi = 0; mi < 2; ++mi)
#pragma unroll
    for (int r = 0; r < 4; ++r) {
      int t = m0 + wm + mi * 16 + quad * 4 + r;
#pragma unroll
      for (int ni = 0; ni < 4; ++ni) {
        int c = n0 + wn + ni * 16 + l16;
        out[(size_t)t * N + c] = acc[mi][ni][r] + bias[c];
      }
    }
}

// ---------------- flash attention (32x32 MFMA, 4-way split-K, in-register P) ---
// 256 blocks x 1024 threads (16 waves = 4 groups x 4 waves). Block (p, bh)
// runs two phases: q-tile qbL = 15-p then qbS = p (128 q rows each; wave w4
// owns 32 rows). Within a phase, the q-tile's 2(qb+1) 64-key tiles are split
// contiguously across the 4 groups; groups with fewer tiles idle-iterate so
// every wave hits the same barrier count. Slot count per block is uniform
// (ceil((qbL+1)/2) + ceil((qbS+1)/2) = 9) -> no tail, 16 waves/CU steady.
// Fixed-m softmax (scale*log2e folded into Q) -> split-K combine is additive;
// 4-way combine through LDS after each phase. QK^T swapped (K as A-operand)
// so P lands in D-layout; converted to the PV B-operand with
// v_cvt_pk_bf16_f32 + v_permlane32_swap_b32 (no LDS bounce, 0 bank conflicts).
// K/V staged in fragment order via global_load_lds, double-buffered, counted
// vmcnt(4) -> loads stay in flight across barriers.
template <bool MASKED>
DEVI void attn32_phase(const bf16_t* __restrict__ Qp, const char* __restrict__ Kg,
                       const char* __restrict__ Vg, const int* __restrict__ mp,
                       unsigned short* __restrict__ cp, char* lds,
                       int b, int bh, int qb) {
  const int tid = threadIdx.x, lane = tid & 63, wid = tid >> 6;
  const int grp = wid >> 2, w4 = wid & 3;
  const int l32 = lane & 31, hi = lane >> 5;

  const int qw = qb * 128 + w4 * 32;       // wave's first q row
  const int qg = qw + l32;                 // this lane's q (as D-col)
  const int nTot = 2 * (qb + 1);           // 64-key tiles in this q-tile's range
  const int qd = nTot >> 2, rm = nTot & 3;
  const int nG  = qd + ((grp < rm) ? 1 : 0);              // my group's tile count
  const int st0 = grp * qd + ((grp < rm) ? grp : rm);     // my first tile
  const int nMax = qd + (rm ? 1 : 0);                     // uniform loop bound
  const int gk0 = st0 * 64;                               // group key base
  char* gB = lds + grp * 32768;            // per-group 32KB (2 x 16KB dbuf)

  // Q fragments (B-operand): B[k = hi*8+j][n = q = l32], d-chunk c
  bf16x8 qf[4];
#pragma unroll
  for (int c = 0; c < 4; ++c)
    qf[c] = *(const bf16x8*)(Qp + (size_t)(qw + l32) * Dh + c * 16 + hi * 8);
  // force the Q-load waits to land here (pre-loop), keeping in-loop vmcnt exact
  asm volatile("" :: "v"((float)qf[3][7]));

  // staging: wave stages K sections {w4*2, w4*2+1} and V sections {w4*2, w4*2+1}
  // K section s = a*4+c : element (key = l32, d = c*16 + hi*8 + j) of chunk a
  // V section s = e*4+kc: element (d = e*32 + l32, key = kc*16 + hi*8 + j)
  int kLds[2], vLds[2], kOff[2], vOff[2];
#pragma unroll
  for (int i = 0; i < 2; ++i) {
    const int s = w4 * 2 + i;
    const int a = s >> 2, c = s & 3;
    kLds[i] = s * 1024;
    kOff[i] = ((a * 32 + l32) * Dh + c * 16 + hi * 8) * 2;
    vLds[i] = 8192 + s * 1024;
    vOff[i] = ((s >> 2) * 32 + l32) * (S * 2) + (((s & 3) * 16 + hi * 8) * 2);
  }

  f32x16 cacc0 = {}, cacc1 = {};
  float lsum = 0.f;

  // prologue: stage tile 0 -> buffer 0
  if (nG > 0) {
    const char* ks = Kg + (size_t)gk0 * (Dh * 2);
    const char* vs = Vg + (size_t)gk0 * 2;
    async_copy16(gB + kLds[0], ks + kOff[0]);
    async_copy16(gB + kLds[1], ks + kOff[1]);
    async_copy16(gB + vLds[0], vs + vOff[0]);
    async_copy16(gB + vLds[1], vs + vOff[1]);
  }

  for (int kt = 0; kt < nMax; ++kt) {
    const int cur = kt & 1;
    const int kb = gk0 + kt * 64;
    const bool act = kt < nG;
    unsigned long long dm = 0;
    if (act) {
      if (kt + 1 < nG) {
        char* dst = gB + (cur ^ 1) * 16384;
        const char* ks = Kg + (size_t)(kb + 64) * (Dh * 2);
        const char* vs = Vg + (size_t)(kb + 64) * 2;
        async_copy16(dst + kLds[0], ks + kOff[0]);
        async_copy16(dst + kLds[1], ks + kOff[1]);
        async_copy16(dst + vLds[0], vs + vOff[0]);
        async_copy16(dst + vLds[1], vs + vOff[1]);
        if (!MASKED) { VMCNT4(); }     // wait only for tile kt's 4 copies
      } else if (!MASKED) {
        VMCNT0();
      }
      if (MASKED) {
        int mk = mp[kb + lane];
        VMCNT0();
        dm = __ballot(mk == 0);
      }
    }
    block_sync();                       // tile kt visible to all waves

    if (act) {
      const bf16_t* sK = (const bf16_t*)(gB + cur * 16384);
      const bf16_t* sV = (const bf16_t*)(gB + cur * 16384 + 8192);
      const bool needC = (kb + 63 > qw);  // causal mask touches this tile?

#pragma unroll
      for (int a = 0; a < 2; ++a) {
        // S^T(32 keys x 32 q) = K . Q^T over d (4 chunks of 16)
        f32x16 st = {};
        __builtin_amdgcn_s_setprio(1);
#pragma unroll
        for (int c = 0; c < 4; ++c) {
          bf16x8 kf = *(const bf16x8*)(sK + (a * 4 + c) * 512 + lane * 8);
          st = __builtin_amdgcn_mfma_f32_32x32x16_bf16(kf, qf[c], st, 0, 0, 0);
        }
        __builtin_amdgcn_s_setprio(0);
        // D layout: col = q = l32, key-in-32 = (r&3) + 8*(r>>2) + 4*hi
        if (MASKED && dm) {
#pragma unroll
          for (int r = 0; r < 16; ++r)
            if ((dm >> (a * 32 + (r & 3) + 8 * (r >> 2) + 4 * hi)) & 1ull) st[r] = -1e30f;
        }
        if (needC) {
          const int kbase = kb + a * 32 + 4 * hi - qg;
#pragma unroll
          for (int r = 0; r < 16; ++r)
            if (kbase + (r & 3) + 8 * (r >> 2) > 0) st[r] = -1e30f;
        }
        // p = exp2(s) (fixed m); pack pairs to bf16 dwords
        unsigned P0[4], P1[4];
#pragma unroll
        for (int m = 0; m < 4; ++m) {
          float p0 = exp2f(st[4 * m + 0]), p1 = exp2f(st[4 * m + 1]);
          float p2 = exp2f(st[4 * m + 2]), p3 = exp2f(st[4 * m + 3]);
          lsum += (p0 + p1) + (p2 + p3);
          P0[m] = cvtpk(p0, p1);
          P1[m] = cvtpk(p2, p3);
        }
        // permlane32_swap -> PV B-operand frags (keys a*32+[0,16) and a*32+[16,32))
        swap32(P0[0], P0[1]); swap32(P1[0], P1[1]);
        swap32(P0[2], P0[3]); swap32(P1[2], P1[3]);
        u32x4 t0 = { P0[0], P1[0], P0[1], P1[1] };
        u32x4 t1 = { P0[2], P1[2], P0[3], P1[3] };
        const bf16x8 f0 = __builtin_bit_cast(bf16x8, t0);
        const bf16x8 f1 = __builtin_bit_cast(bf16x8, t1);
        // ctx^T += V^T . P^T
        __builtin_amdgcn_s_setprio(1);
        {
          bf16x8 v00 = *(const bf16x8*)(sV + (0 + a * 2 + 0) * 512 + lane * 8);
          cacc0 = __builtin_amdgcn_mfma_f32_32x32x16_bf16(v00, f0, cacc0, 0, 0, 0);
          bf16x8 v01 = *(const bf16x8*)(sV + (0 + a * 2 + 1) * 512 + lane * 8);
          cacc0 = __builtin_amdgcn_mfma_f32_32x32x16_bf16(v01, f1, cacc0, 0, 0, 0);
          bf16x8 v10 = *(const bf16x8*)(sV + (4 + a * 2 + 0) * 512 + lane * 8);
          cacc1 = __builtin_amdgcn_mfma_f32_32x32x16_bf16(v10, f0, cacc1, 0, 0, 0);
          bf16x8 v11 = *(const bf16x8*)(sV + (4 + a * 2 + 1) * 512 + lane * 8);
          cacc1 = __builtin_amdgcn_mfma_f32_32x32x16_bf16(v11, f1, cacc1, 0, 0, 0);
        }
        __builtin_amdgcn_s_setprio(0);
      }
    }
    block_sync();                       // buf[cur] fully consumed
  }

  // ---- 4-way split-K combine: grp1..3 -> LDS, grp0 adds, normalizes, writes ----
  // region(j, w4) = 8448 bytes: 8 chunks of [64 lanes x 16B] + 64 lsum f32
  if (grp != 0) {
    char* rb = lds + (size_t)((grp - 1) * 4 + w4) * 8448;
#pragma unroll
    for (int c = 0; c < 4; ++c) {
      f32x4 v = { cacc0[4 * c], cacc0[4 * c + 1], cacc0[4 * c + 2], cacc0[4 * c + 3] };
      *(f32x4*)(rb + c * 1024 + lane * 16) = v;
    }
#pragma unroll
    for (int c = 0; c < 4; ++c) {
      f32x4 v = { cacc1[4 * c], cacc1[4 * c + 1], cacc1[4 * c + 2], cacc1[4 * c + 3] };
      *(f32x4*)(rb + (4 + c) * 1024 + lane * 16) = v;
    }
    *(float*)(rb + 8192 + lane * 4) = lsum;
  }
  asm volatile("s_waitcnt lgkmcnt(0)" ::: "memory");
  block_sync();
  if (grp == 0) {
#pragma unroll
    for (int j = 1; j < 4; ++j) {
      const char* rb = lds + (size_t)((j - 1) * 4 + w4) * 8448;
#pragma unroll
      for (int c = 0; c < 4; ++c) {
        f32x4 v = *(const f32x4*)(rb + c * 1024 + lane * 16);
        cacc0[4 * c] += v[0]; cacc0[4 * c + 1] += v[1];
        cacc0[4 * c + 2] += v[2]; cacc0[4 * c + 3] += v[3];
      }
#pragma unroll
      for (int c = 0; c < 4; ++c) {
        f32x4 v = *(const f32x4*)(rb + (4 + c) * 1024 + lane * 16);
        cacc1[4 * c] += v[0]; cacc1[4 * c + 1] += v[1];
        cacc1[4 * c + 2] += v[2]; cacc1[4 * c + 3] += v[3];
      }
      lsum += *(const float*)(rb + 8192 + lane * 4);
    }
    lsum += __shfl_xor(lsum, 32);
    const float inv = 1.0f / lsum;
    const size_t base = ((size_t)(b * S + qw + l32)) * N + (size_t)(bh & 15) * Dh;
#pragma unroll
    for (int m = 0; m < 4; ++m) {
      const int d0 = m * 8 + 4 * hi;     // d = (r&3) + 8m + 4hi
      u16x4 o0 = { f2bf(cacc0[4 * m + 0] * inv), f2bf(cacc0[4 * m + 1] * inv),
                   f2bf(cacc0[4 * m + 2] * inv), f2bf(cacc0[4 * m + 3] * inv) };
      *(u16x4*)&cp[base + d0] = o0;
      u16x4 o1 = { f2bf(cacc1[4 * m + 0] * inv), f2bf(cacc1[4 * m + 1] * inv),
                   f2bf(cacc1[4 * m + 2] * inv), f2bf(cacc1[4 * m + 3] * inv) };
      *(u16x4*)&cp[base + 32 + d0] = o1;
    }
  }
  block_sync();    // combine regions free before next phase's staging
}

__global__ __launch_bounds__(1024, 4) void attn_kernel(
    const bf16_t* __restrict__ Q, const bf16_t* __restrict__ Kb,
    const bf16_t* __restrict__ Vt, const int* __restrict__ mask,
    bf16_t* __restrict__ ctx) {
  __shared__ f32x4 ldsbuf[8192];               // 128 KB: 4 groups x 32KB dbuf

  const int idx = blockIdx.x;                  // 256 blocks
  const int p   = idx >> 5;                    // 0..7
  const int bh  = idx & 31;
  const int qbL = 15 - p, qbS = p;             // phases sum to 9 slots for all p
  const int b   = bh >> 4;
  const int lane = threadIdx.x & 63;

  const bf16_t* Qp = Q + (size_t)bh * S * Dh;
  const char*   Kg = (const char*)(Kb + (size_t)bh * S * Dh);
  const char*   Vg = (const char*)(Vt + (size_t)bh * Dh * S);
  const int*    mp = mask + b * S;

  // one pass over the mask row: all-alive -> fast path with zero in-loop
  // mask vmem (keeps the counted-vmcnt accounting exact)
  int dead = 0;
  const int4* mp4 = (const int4*)mp;
  for (int c = lane; c < S / 4; c += 64) {
    int4 m = mp4[c];
    dead |= (m.x == 0) | (m.y == 0) | (m.z == 0) | (m.w == 0);
  }
  const bool anydead = __ballot(dead != 0) != 0ull;

  unsigned short* cp = (unsigned short*)ctx;
  char* lds = (char*)ldsbuf;
  if (!anydead) {
#pragma unroll 1
    for (int t = 0; t < 2; ++t)
      attn32_phase<false>(Qp, Kg, Vg, mp, cp, lds, b, bh, t ? qbS : qbL);
  } else {
#pragma unroll 1
    for (int t = 0; t < 2; ++t)
      attn32_phase<true>(Qp, Kg, Vg, mp, cp, lds, b, bh, t ? qbS : qbL);
  }
}

// ---------------- launcher ----------------

extern "C" void kernel_launch(void* const* d_in, const int* in_sizes, int n_in,
                              void* d_out, int out_size, void* d_ws, size_t ws_size,
                              hipStream_t stream) {
  const float* x  = (const float*)d_in[0];
  const int*  msk = (const int*)d_in[1];
  const float* Wq = (const float*)d_in[2];
  const float* bq = (const float*)d_in[3];
  const float* Wk = (const float*)d_in[4];
  const float* bk = (const float*)d_in[5];
  const float* Wv = (const float*)d_in[6];
  const float* bv = (const float*)d_in[7];
  const float* Wo = (const float*)d_in[8];
  const float* bo = (const float*)d_in[9];
  float* out = (float*)d_out;
  (void)in_sizes; (void)n_in; (void)out_size; (void)ws_size;

  char* ws = (char*)d_ws;
  bf16_t* xb   = (bf16_t*)(ws);                      // 8 MB  [4096][1024]
  bf16_t* WT   = (bf16_t*)(ws + (8u  << 20));        // 8 MB  4 x [1024][1024] (N-major)
  bf16_t* qkv  = (bf16_t*)(ws + (16u << 20));        // 24 MB Q,K,V each [B,H,S,D]
  bf16_t* Qb   = qkv;
  bf16_t* Kbuf = qkv + (size_t)1 * M * N;
  bf16_t* Vb   = qkv + (size_t)2 * M * N;
  bf16_t* Vt   = xb;                                  // alias: xb dead after QKV GEMM
  bf16_t* ctx  = Vb;                                  // alias: V[B,H,S,D] dead after vtrans
  float* ropeC = (float*)(ws + (40u << 20));          // 256 KB
  float* ropeS = ropeC + (size_t)S * 32;              // 256 KB

  prep_kernel<<<5376, 256, 0, stream>>>(x, xb, Wq, Wk, Wv, Wo, WT, ropeC, ropeS);
  gemm_qkv_kernel<<<dim3(8, 32, 3), 256, 0, stream>>>(xb, WT, bq, bk, bv, qkv, ropeC, ropeS);
  vtrans_kernel<<<dim3(32, 32), 256, 0, stream>>>(Vb, Vt);
  attn_kernel<<<256, 1024, 0, stream>>>(Qb, Kbuf, Vt, msk, ctx);
  gemm_o_kernel<<<dim3(8, 64), 256, 0, stream>>>(ctx, WT + (size_t)3 * Kd * N, bo, out);
}

// Round 4
// 201.804 us; speedup vs baseline: 1.1110x; 1.1110x over previous
//
#include <hip/hip_runtime.h>
#include <cstdint>
#include <cstddef>

#define DEVI __device__ __forceinline__

typedef __bf16 bf16_t;
typedef __bf16 bf16x4 __attribute__((ext_vector_type(4)));
typedef __bf16 bf16x8 __attribute__((ext_vector_type(8)));
typedef float  f32x4  __attribute__((ext_vector_type(4)));
typedef float  f32x16 __attribute__((ext_vector_type(16)));
typedef unsigned short u16x4 __attribute__((ext_vector_type(4)));
typedef unsigned int   u32x4 __attribute__((ext_vector_type(4)));

static constexpr int Bz = 2, S = 2048, E = 1024, H = 16, Dh = 64;
static constexpr int M  = Bz * S;   // 4096 tokens
static constexpr int N  = H * Dh;   // 1024
static constexpr int Kd = E;        // 1024

DEVI unsigned short f2bf(float f) {
  unsigned u = __builtin_bit_cast(unsigned, f);
  return (unsigned short)((u + 0x7fffu + ((u >> 16) & 1u)) >> 16);
}

DEVI void async_copy16(void* lds, const void* g) {
  __builtin_amdgcn_global_load_lds((__attribute__((address_space(1))) void*)(g),
                                   (__attribute__((address_space(3))) void*)(lds), 16, 0, 0);
}

DEVI void block_sync() { asm volatile("s_barrier" ::: "memory"); }
#define VMCNT4() asm volatile("s_waitcnt vmcnt(4)" ::: "memory")
#define VMCNT0() asm volatile("s_waitcnt vmcnt(0)" ::: "memory")

// pack two f32 -> dword of two bf16 (RNE)
DEVI unsigned cvtpk(float lo, float hi) {
  unsigned r;
  asm("v_cvt_pk_bf16_f32 %0, %1, %2" : "=v"(r) : "v"(lo), "v"(hi));
  return r;
}
// swap x's lanes 32-63 with y's lanes 0-31
DEVI void swap32(unsigned& x, unsigned& y) {
  asm("v_permlane32_swap_b32 %0, %1" : "+v"(x), "+v"(y));
}

// ---------------- fused prep: convx | wtrans | rope table ----------------
__global__ void prep_kernel(const float* __restrict__ x, bf16_t* __restrict__ xb,
                            const float* __restrict__ Wq, const float* __restrict__ Wk,
                            const float* __restrict__ Wv, const float* __restrict__ Wo,
                            bf16_t* __restrict__ WtBase,
                            float* __restrict__ ropeC, float* __restrict__ ropeS) {
  __shared__ unsigned short tile[64][68];
  const int blk = blockIdx.x, tid = threadIdx.x;
  if (blk < 4096) {
    // x fp32 -> bf16
    int i = blk * 256 + tid;
    float4 v = ((const float4*)x)[i];
    u16x4 o = { f2bf(v.x), f2bf(v.y), f2bf(v.z), f2bf(v.w) };
    ((u16x4*)xb)[i] = o;
  } else if (blk < 5120) {
    // weight fp32 [K][N] -> bf16 [N][K]
    const int i = blk - 4096;
    const int z = i >> 8, rest = i & 255;
    const int n0 = (rest & 15) * 64, k0 = (rest >> 4) * 64;
    const float* W = (z == 0) ? Wq : (z == 1) ? Wk : (z == 2) ? Wv : Wo;
    unsigned short* T = (unsigned short*)(WtBase + (size_t)z * Kd * N);
    for (int e = tid; e < 1024; e += 256) {
      int r = e >> 4, c4 = (e & 15) * 4;
      float4 v = *(const float4*)(W + (size_t)(k0 + r) * N + n0 + c4);
      u16x4 o = { f2bf(v.x), f2bf(v.y), f2bf(v.z), f2bf(v.w) };
      *(u16x4*)&tile[r][c4] = o;
    }
    __syncthreads();
    for (int e = tid; e < 1024; e += 256) {
      int r = e >> 4, c4 = (e & 15) * 4;
      u16x4 o = { tile[c4][r], tile[c4 + 1][r], tile[c4 + 2][r], tile[c4 + 3][r] };
      *(u16x4*)&T[(size_t)(n0 + r) * Kd + k0 + c4] = o;
    }
  } else {
    int i = (blk - 5120) * 256 + tid;            // 65536 = 2048*32
    int pos = i >> 5, j = i & 31;
    float inv = exp2f(-(float)j * 0.41524101186092029f);   // log2(10000)/32
    float ang = (float)pos * inv;
    ropeC[i] = cosf(ang);
    ropeS[i] = sinf(ang);
  }
}

// bf16 [BH][S][D] -> bf16 [BH][D][S]
__global__ void vtrans_kernel(const bf16_t* __restrict__ V, bf16_t* __restrict__ Vt) {
  __shared__ unsigned short tile[64][68];
  const int bh = blockIdx.y;
  const int s0 = blockIdx.x * 64;
  const unsigned short* Vp = (const unsigned short*)V + (size_t)bh * S * Dh;
  unsigned short* Tp = (unsigned short*)Vt + (size_t)bh * Dh * S;
  const int tid = threadIdx.x;
  for (int e = tid; e < 1024; e += 256) {
    int r = e >> 4, c4 = (e & 15) * 4;
    u16x4 v = *(const u16x4*)(Vp + (size_t)(s0 + r) * Dh + c4);
    *(u16x4*)&tile[r][c4] = v;
  }
  __syncthreads();
  for (int e = tid; e < 1024; e += 256) {
    int d = e >> 4, s4 = (e & 15) * 4;
    u16x4 o = { tile[s4][d], tile[s4 + 1][d], tile[s4 + 2][d], tile[s4 + 3][d] };
    *(u16x4*)&Tp[(size_t)d * S + s0 + s4] = o;
  }
}

// ---------------- GEMM core (128x128 tile, BK=32, global_load_lds) ----------------

DEVI void gemm_mainloop(const bf16_t* __restrict__ A, const bf16_t* __restrict__ Bt,
                        bf16_t* sA, bf16_t* sB, int m0, int n0, f32x4 (&acc)[4][4]) {
  const int tid  = threadIdx.x;
  const int lane = tid & 63;
  const int wid  = tid >> 6;
  const int l16  = lane & 15;
  const int quad = lane >> 4;
  const int wm = (wid >> 1) * 64;
  const int wn = (wid & 1) * 64;
  const int o0 = wid * 2048 + lane * 16;   // byte offset within 8KB tile
  const int o1 = o0 + 1024;
  const int r0 = o0 >> 6, c0 = o0 & 63;
  const int r1 = o1 >> 6, c1 = o1 & 63;
  const char* Ab = (const char*)A;
  const char* Bb = (const char*)Bt;
  char* sAc = (char*)sA;
  char* sBc = (char*)sB;

  for (int k0 = 0; k0 < Kd; k0 += 32) {
    __syncthreads();
    async_copy16(sAc + wid * 2048,        Ab + ((size_t)(m0 + r0) * Kd + k0) * 2 + c0);
    async_copy16(sAc + wid * 2048 + 1024, Ab + ((size_t)(m0 + r1) * Kd + k0) * 2 + c1);
    async_copy16(sBc + wid * 2048,        Bb + ((size_t)(n0 + r0) * Kd + k0) * 2 + c0);
    async_copy16(sBc + wid * 2048 + 1024, Bb + ((size_t)(n0 + r1) * Kd + k0) * 2 + c1);
    __syncthreads();
    bf16x8 af[4], bfv[4];
#pragma unroll
    for (int mi = 0; mi < 4; ++mi)
      af[mi] = *(const bf16x8*)(sA + (wm + mi * 16 + l16) * 32 + quad * 8);
#pragma unroll
    for (int ni = 0; ni < 4; ++ni)
      bfv[ni] = *(const bf16x8*)(sB + (wn + ni * 16 + l16) * 32 + quad * 8);
#pragma unroll
    for (int mi = 0; mi < 4; ++mi)
#pragma unroll
      for (int ni = 0; ni < 4; ++ni)
        acc[mi][ni] = __builtin_amdgcn_mfma_f32_16x16x32_bf16(af[mi], bfv[ni], acc[mi][ni], 0, 0, 0);
  }
}

// z = 0:Q(RoPE+scale) 1:K(RoPE) 2:V ; out layout [B,H,S,D] bf16
__global__ __launch_bounds__(256, 3) void gemm_qkv_kernel(
    const bf16_t* __restrict__ xb, const bf16_t* __restrict__ WtBase,
    const float* __restrict__ bq, const float* __restrict__ bk, const float* __restrict__ bv,
    bf16_t* __restrict__ outBase,
    const float* __restrict__ ropeC, const float* __restrict__ ropeS) {
  __shared__ bf16_t sA[4096], sB[4096];
  const int z = blockIdx.z;
  const bf16_t* Bt = WtBase + (size_t)z * Kd * N;
  const float* bias = (z == 0) ? bq : (z == 1) ? bk : bv;
  unsigned short* outp = (unsigned short*)(outBase + (size_t)z * M * N);
  const int n0 = blockIdx.x * 128, m0 = blockIdx.y * 128;
  f32x4 acc[4][4] = {};
  gemm_mainloop(xb, Bt, sA, sB, m0, n0, acc);

  const int tid = threadIdx.x, lane = tid & 63, wid = tid >> 6;
  const int l16 = lane & 15, quad = lane >> 4;
  const int wm = (wid >> 1) * 64, wn = (wid & 1) * 64;
  const int cbase = n0 + wn;          // 64-aligned -> one head per wave slab
  const int h = cbase >> 6;

  if (z < 2) {
    // Q gets 0.125 (=1/sqrt(D)) * log2(e) folded in so attention can use exp2
    const float qs = (z == 0) ? 0.18033688011112042f : 1.0f;
#pragma unroll
    for (int mi = 0; mi < 4; ++mi)
#pragma unroll
      for (int r = 0; r < 4; ++r) {
        int t = m0 + wm + mi * 16 + quad * 4 + r;
        int bb = t >> 11, s = t & (S - 1);
        size_t obase = ((size_t)(bb * H + h) * S + s) * Dh;
#pragma unroll
        for (int np = 0; np < 2; ++np) {
          int j = np * 16 + l16;                 // = d (low half), d-32 (high half)
          float cc = ropeC[s * 32 + j];
          float ss = ropeS[s * 32 + j];
          float xlo = acc[mi][np][r]     + bias[cbase + j];
          float xhi = acc[mi][np + 2][r] + bias[cbase + j + 32];
          outp[obase + j]      = f2bf((xlo * cc - xhi * ss) * qs);
          outp[obase + j + 32] = f2bf((xhi * cc + xlo * ss) * qs);
        }
      }
  } else {
#pragma unroll
    for (int mi = 0; mi < 4; ++mi)
#pragma unroll
      for (int r = 0; r < 4; ++r) {
        int t = m0 + wm + mi * 16 + quad * 4 + r;
        int bb = t >> 11, s = t & (S - 1);
        size_t obase = ((size_t)(bb * H + h) * S + s) * Dh;
#pragma unroll
        for (int ni = 0; ni < 4; ++ni) {
          int d = ni * 16 + l16;
          outp[obase + d] = f2bf(acc[mi][ni][r] + bias[cbase + d]);
        }
      }
  }
}

// output GEMM: 64(m) x 128(n) tiles -> 512 blocks (2/CU)
__global__ __launch_bounds__(256, 4) void gemm_o_kernel(
    const bf16_t* __restrict__ A, const bf16_t* __restrict__ Bt,
    const float* __restrict__ bias, float* __restrict__ out) {
  __shared__ bf16_t sA[2048], sB[4096];     // 4KB A (64x32), 8KB B (128x32)
  const int n0 = blockIdx.x * 128, m0 = blockIdx.y * 64;
  const int tid = threadIdx.x, lane = tid & 63, wid = tid >> 6;
  const int l16 = lane & 15, quad = lane >> 4;
  const int wm = (wid >> 1) * 32, wn = (wid & 1) * 64;
  const int rowoff = lane >> 2, col8 = (lane & 3) * 8;
  const char* Ab = (const char*)A;
  const char* Bb = (const char*)Bt;
  char* sAc = (char*)sA;
  char* sBc = (char*)sB;
  f32x4 acc[2][4] = {};

  for (int k0 = 0; k0 < Kd; k0 += 32) {
    __syncthreads();
    async_copy16(sAc + wid * 1024,
                 Ab + ((size_t)(m0 + wid * 16 + rowoff) * Kd + k0 + col8) * 2);
    async_copy16(sBc + (wid * 2) * 1024,
                 Bb + ((size_t)(n0 + wid * 32 + rowoff) * Kd + k0 + col8) * 2);
    async_copy16(sBc + (wid * 2 + 1) * 1024,
                 Bb + ((size_t)(n0 + wid * 32 + 16 + rowoff) * Kd + k0 + col8) * 2);
    __syncthreads();
    bf16x8 af[2], bfv[4];
#pragma unroll
    for (int mi = 0; mi < 2; ++mi)
      af[mi] = *(const bf16x8*)(sA + (wm + mi * 16 + l16) * 32 + quad * 8);
#pragma unroll
    for (int ni = 0; ni < 4; ++ni)
      bfv[ni] = *(const bf16x8*)(sB + (wn + ni * 16 + l16) * 32 + quad * 8);
#pragma unroll
    for (int mi = 0; mi < 2; ++mi)
#pragma unroll
      for (int ni = 0; ni < 4; ++ni)
        acc[mi][ni] = __builtin_amdgcn_mfma_f32_16x16x32_bf16(af[mi], bfv[ni], acc[mi][ni], 0, 0, 0);
  }
#pragma unroll
  for (int mi = 0; mi < 2; ++mi)
#pragma unroll
    for (int r = 0; r < 4; ++r) {
      int t = m0 + wm + mi * 16 + quad * 4 + r;
#pragma unroll
      for (int ni = 0; ni < 4; ++ni) {
        int c = n0 + wn + ni * 16 + l16;
        out[(size_t)t * N + c] = acc[mi][ni][r] + bias[c];
      }
    }
}

// ------- flash attention: 32x32 MFMA, 4-way split-K, 2 waves/group, 32-key tiles ---
// 512 blocks x 512 threads (8 waves = 4 groups x 2 waves). Block (p, bh) runs
// two phases: q-tile qt = 31-p then qt = p (64 q rows each; wave w2 owns 32).
// Within a phase the 2(qt+1) 32-key tiles split contiguously across 4 groups;
// slots/block = ceil((32-p)/2) + ceil((p+1)/2) = 17 for ALL blocks -> 512
// uniform blocks, 2 blocks/CU (67.5KB LDS), 16 waves/CU steady, no tail.
// Fixed-m softmax (scale*log2e folded into Q) -> split-K combine additive.
// QK^T swapped (K as A-operand) so P lands in D-layout; converted to the PV
// B-operand with v_cvt_pk_bf16_f32 + v_permlane32_swap_b32 (no LDS bounce).
// K/V staged fragment-order via global_load_lds, double-buffered, counted
// vmcnt(4). Combine is balanced: all 8 waves write rotated partials, each
// wave reduces 8 output rows (rotation (d+4*row)&63 -> bank-uniform b128).
template <bool MASKED>
DEVI void attn32_phase(const bf16_t* __restrict__ Qp, const char* __restrict__ Kg,
                       const char* __restrict__ Vg, const int* __restrict__ mp,
                       unsigned short* __restrict__ cp, char* lds,
                       int b, int bh, int qt) {
  const int tid = threadIdx.x, lane = tid & 63, wid = tid >> 6;
  const int grp = wid >> 1, w2 = wid & 1;
  const int l32 = lane & 31, hi = lane >> 5;

  const int qw = qt * 64 + w2 * 32;        // wave's first q row
  const int qg = qw + l32;                 // this lane's q (as D-col)
  const int nk = 2 * (qt + 1);             // 32-key tiles in range
  const int qd = nk >> 2, rm = nk & 3;     // rm in {0,2}
  const int nG  = qd + ((grp < rm) ? 1 : 0);
  const int st0 = grp * qd + ((grp < rm) ? grp : rm);
  const int nMax = qd + (rm ? 1 : 0);      // uniform loop bound (same all groups)
  const int gk0 = st0 * 32;                // group's first key
  char* gB = lds + grp * 16384;            // per-group 16KB (2 x 8KB dbuf)

  // Q fragments (B-operand): B[k = hi*8+j][n = q = l32], d-chunk c
  bf16x8 qf[4];
#pragma unroll
  for (int c = 0; c < 4; ++c)
    qf[c] = *(const bf16x8*)(Qp + (size_t)(qw + l32) * Dh + c * 16 + hi * 8);
  // force Q-load waits here (pre-loop), keeping in-loop vmcnt accounting exact
  asm volatile("" :: "v"((float)qf[3][7]));

  // fragment-order staging: w2=0 stages the 4 K sections, w2=1 the 4 V sections
  // K section c: lane -> K[key=l32][d = c*16 + hi*8 ..+7]
  // V section e*2+kc: lane -> V^T[d = e*32+l32][key = kc*16 + hi*8 ..+7]
  const char* gsrc = w2 ? Vg : Kg;
  const size_t keyB = w2 ? 2u : 128u;      // bytes per key step in source
  int sLds[4], sOff[4];
#pragma unroll
  for (int i = 0; i < 4; ++i) {
    sLds[i] = (w2 * 4 + i) * 1024;
    if (w2 == 0) sOff[i] = (l32 * 64 + i * 16 + hi * 8) * 2;
    else {
      int e = i >> 1, kc = i & 1;
      sOff[i] = ((e * 32 + l32) * S + kc * 16 + hi * 8) * 2;
    }
  }

  f32x16 cacc0 = {}, cacc1 = {};
  float lsum = 0.f;

  // prologue: stage tile 0 -> buffer 0
  if (nG > 0) {
    const char* bp = gsrc + (size_t)gk0 * keyB;
#pragma unroll
    for (int i = 0; i < 4; ++i) async_copy16(gB + sLds[i], bp + sOff[i]);
  }

  for (int kt = 0; kt < nMax; ++kt) {
    const int cur = kt & 1;
    const int kb = gk0 + kt * 32;
    const bool act = kt < nG;
    unsigned long long dm = 0;
    if (act) {
      if (kt + 1 < nG) {
        const char* bp = gsrc + (size_t)(kb + 32) * keyB;
        char* dst = gB + (cur ^ 1) * 8192;
#pragma unroll
        for (int i = 0; i < 4; ++i) async_copy16(dst + sLds[i], bp + sOff[i]);
        if (!MASKED) { VMCNT4(); }     // wait only for tile kt's 4 copies
      } else if (!MASKED) {
        VMCNT0();
      }
      if (MASKED) {
        int mk = mp[kb + l32];
        VMCNT0();
        dm = __ballot(mk == 0);
      }
    }
    block_sync();                       // tile kt visible to all waves

    if (act) {
      const bf16_t* sT = (const bf16_t*)(gB + cur * 8192);
      // S^T(32 keys x 32 q) = K . Q^T over d (4 chunks of 16)
      f32x16 st = {};
      __builtin_amdgcn_s_setprio(1);
#pragma unroll
      for (int c = 0; c < 4; ++c) {
        bf16x8 kf = *(const bf16x8*)(sT + c * 512 + lane * 8);
        st = __builtin_amdgcn_mfma_f32_32x32x16_bf16(kf, qf[c], st, 0, 0, 0);
      }
      __builtin_amdgcn_s_setprio(0);
      // D layout: col = q = l32, key-in-32 = (r&3) + 8*(r>>2) + 4*hi
      if (MASKED && dm) {
#pragma unroll
        for (int r = 0; r < 16; ++r)
          if ((dm >> ((r & 3) + 8 * (r >> 2) + 4 * hi)) & 1ull) st[r] = -1e30f;
      }
      if (kb + 31 > qw) {               // causal mask touches this tile
        const int kbase = kb + 4 * hi - qg;
#pragma unroll
        for (int r = 0; r < 16; ++r)
          if (kbase + (r & 3) + 8 * (r >> 2) > 0) st[r] = -1e30f;
      }
      // p = exp2(s) (fixed m); pack pairs to bf16 dwords
      unsigned P0[4], P1[4];
#pragma unroll
      for (int m = 0; m < 4; ++m) {
        float p0 = exp2f(st[4 * m + 0]), p1 = exp2f(st[4 * m + 1]);
        float p2 = exp2f(st[4 * m + 2]), p3 = exp2f(st[4 * m + 3]);
        lsum += (p0 + p1) + (p2 + p3);
        P0[m] = cvtpk(p0, p1);
        P1[m] = cvtpk(p2, p3);
      }
      // permlane32_swap -> PV B-operand frags (keys [0,16) and [16,32))
      swap32(P0[0], P0[1]); swap32(P1[0], P1[1]);
      swap32(P0[2], P0[3]); swap32(P1[2], P1[3]);
      u32x4 t0 = { P0[0], P1[0], P0[1], P1[1] };
      u32x4 t1 = { P0[2], P1[2], P0[3], P1[3] };
      const bf16x8 f0 = __builtin_bit_cast(bf16x8, t0);
      const bf16x8 f1 = __builtin_bit_cast(bf16x8, t1);
      // ctx^T += V^T . P^T
      __builtin_amdgcn_s_setprio(1);
      {
        bf16x8 v00 = *(const bf16x8*)(sT + 2048 + 0 * 512 + lane * 8);
        cacc0 = __builtin_amdgcn_mfma_f32_32x32x16_bf16(v00, f0, cacc0, 0, 0, 0);
        bf16x8 v01 = *(const bf16x8*)(sT + 2048 + 1 * 512 + lane * 8);
        cacc0 = __builtin_amdgcn_mfma_f32_32x32x16_bf16(v01, f1, cacc0, 0, 0, 0);
        bf16x8 v10 = *(const bf16x8*)(sT + 2048 + 2 * 512 + lane * 8);
        cacc1 = __builtin_amdgcn_mfma_f32_32x32x16_bf16(v10, f0, cacc1, 0, 0, 0);
        bf16x8 v11 = *(const bf16x8*)(sT + 2048 + 3 * 512 + lane * 8);
        cacc1 = __builtin_amdgcn_mfma_f32_32x32x16_bf16(v11, f1, cacc1, 0, 0, 0);
      }
      __builtin_amdgcn_s_setprio(0);
    }
    block_sync();                       // buf[cur] fully consumed
  }

  // ---- balanced 4-way combine: all 8 waves store rotated partials, then each
  // wave reduces 8 output rows. region: f32 reg[grp][row 64][d 64] (=64KB,
  // reuses staging space) + lsums f32[grp*2+hi][row 64] at +64KB.
  float* reg = (float*)lds;
  {
    const int row = w2 * 32 + l32;
    float* rb = reg + grp * 4096 + row * 64;
#pragma unroll
    for (int m = 0; m < 4; ++m) {
      f32x4 v = { cacc0[4 * m], cacc0[4 * m + 1], cacc0[4 * m + 2], cacc0[4 * m + 3] };
      *(f32x4*)(rb + ((8 * m + 4 * hi + 4 * row) & 63)) = v;
    }
#pragma unroll
    for (int m = 0; m < 4; ++m) {
      f32x4 v = { cacc1[4 * m], cacc1[4 * m + 1], cacc1[4 * m + 2], cacc1[4 * m + 3] };
      *(f32x4*)(rb + ((32 + 8 * m + 4 * hi + 4 * row) & 63)) = v;
    }
    reg[16384 + (grp * 2 + hi) * 64 + row] = lsum;
  }
  asm volatile("s_waitcnt lgkmcnt(0)" ::: "memory");
  block_sync();
  {
    const int orow = wid * 8 + (lane & 7);   // each wave owns 8 rows
    const int d0 = (lane >> 3) * 8;          // 8 d-slices of 8
    f32x4 oa = {}, ob = {};
    float ls = 0.f;
#pragma unroll
    for (int g = 0; g < 4; ++g) {
      const float* rb = reg + g * 4096 + orow * 64;
      f32x4 va = *(const f32x4*)(rb + ((d0 + 4 * orow) & 63));
      f32x4 vb = *(const f32x4*)(rb + ((d0 + 4 + 4 * orow) & 63));
      oa += va; ob += vb;
      ls += reg[16384 + (g * 2 + 0) * 64 + orow] + reg[16384 + (g * 2 + 1) * 64 + orow];
    }
    const float inv = 1.0f / ls;
    const size_t base = ((size_t)(b * S + qt * 64 + orow)) * N + (size_t)(bh & 15) * Dh + d0;
    u16x4 o0 = { f2bf(oa[0] * inv), f2bf(oa[1] * inv), f2bf(oa[2] * inv), f2bf(oa[3] * inv) };
    u16x4 o1 = { f2bf(ob[0] * inv), f2bf(ob[1] * inv), f2bf(ob[2] * inv), f2bf(ob[3] * inv) };
    *(u16x4*)&cp[base] = o0;
    *(u16x4*)&cp[base + 4] = o1;
  }
  block_sync();    // combine region free before next phase's staging
}

__global__ __launch_bounds__(512, 4) void attn_kernel(
    const bf16_t* __restrict__ Q, const bf16_t* __restrict__ Kb,
    const bf16_t* __restrict__ Vt, const int* __restrict__ mask,
    bf16_t* __restrict__ ctx) {
  __shared__ f32x4 ldsbuf[4224];               // 67.5 KB (64KB stage/combine + lsums)

  const int idx = blockIdx.x;                  // 512 blocks
  const int p   = idx >> 5;                    // 0..15
  const int bh  = idx & 31;
  const int qtL = 31 - p, qtS = p;             // slots: ceil((32-p)/2)+ceil((p+1)/2)=17
  const int b   = bh >> 4;
  const int lane = threadIdx.x & 63;

  const bf16_t* Qp = Q + (size_t)bh * S * Dh;
  const char*   Kg = (const char*)(Kb + (size_t)bh * S * Dh);
  const char*   Vg = (const char*)(Vt + (size_t)bh * Dh * S);
  const int*    mp = mask + b * S;

  // one pass over the mask row: all-alive -> fast path with zero in-loop
  // mask vmem (keeps the counted-vmcnt accounting exact)
  int dead = 0;
  const int4* mp4 = (const int4*)mp;
  for (int c = lane; c < S / 4; c += 64) {
    int4 m = mp4[c];
    dead |= (m.x == 0) | (m.y == 0) | (m.z == 0) | (m.w == 0);
  }
  const bool anydead = __ballot(dead != 0) != 0ull;

  unsigned short* cp = (unsigned short*)ctx;
  char* lds = (char*)ldsbuf;
  if (!anydead) {
    attn32_phase<false>(Qp, Kg, Vg, mp, cp, lds, b, bh, qtL);
    attn32_phase<false>(Qp, Kg, Vg, mp, cp, lds, b, bh, qtS);
  } else {
    attn32_phase<true>(Qp, Kg, Vg, mp, cp, lds, b, bh, qtL);
    attn32_phase<true>(Qp, Kg, Vg, mp, cp, lds, b, bh, qtS);
  }
}

// ---------------- launcher ----------------

extern "C" void kernel_launch(void* const* d_in, const int* in_sizes, int n_in,
                              void* d_out, int out_size, void* d_ws, size_t ws_size,
                              hipStream_t stream) {
  const float* x  = (const float*)d_in[0];
  const int*  msk = (const int*)d_in[1];
  const float* Wq = (const float*)d_in[2];
  const float* bq = (const float*)d_in[3];
  const float* Wk = (const float*)d_in[4];
  const float* bk = (const float*)d_in[5];
  const float* Wv = (const float*)d_in[6];
  const float* bv = (const float*)d_in[7];
  const float* Wo = (const float*)d_in[8];
  const float* bo = (const float*)d_in[9];
  float* out = (float*)d_out;
  (void)in_sizes; (void)n_in; (void)out_size; (void)ws_size;

  char* ws = (char*)d_ws;
  bf16_t* xb   = (bf16_t*)(ws);                      // 8 MB  [4096][1024]
  bf16_t* WT   = (bf16_t*)(ws + (8u  << 20));        // 8 MB  4 x [1024][1024] (N-major)
  bf16_t* qkv  = (bf16_t*)(ws + (16u << 20));        // 24 MB Q,K,V each [B,H,S,D]
  bf16_t* Qb   = qkv;
  bf16_t* Kbuf = qkv + (size_t)1 * M * N;
  bf16_t* Vb   = qkv + (size_t)2 * M * N;
  bf16_t* Vt   = xb;                                  // alias: xb dead after QKV GEMM
  bf16_t* ctx  = Vb;                                  // alias: V[B,H,S,D] dead after vtrans
  float* ropeC = (float*)(ws + (40u << 20));          // 256 KB
  float* ropeS = ropeC + (size_t)S * 32;              // 256 KB

  prep_kernel<<<5376, 256, 0, stream>>>(x, xb, Wq, Wk, Wv, Wo, WT, ropeC, ropeS);
  gemm_qkv_kernel<<<dim3(8, 32, 3), 256, 0, stream>>>(xb, WT, bq, bk, bv, qkv, ropeC, ropeS);
  vtrans_kernel<<<dim3(32, 32), 256, 0, stream>>>(Vb, Vt);
  attn_kernel<<<512, 512, 0, stream>>>(Qb, Kbuf, Vt, msk, ctx);
  gemm_o_kernel<<<dim3(8, 64), 256, 0, stream>>>(ctx, WT + (size_t)3 * Kd * N, bo, out);
}

// Round 6
// 198.394 us; speedup vs baseline: 1.1301x; 1.0172x over previous
//
#include <hip/hip_runtime.h>
#include <cstdint>
#include <cstddef>

#define DEVI __device__ __forceinline__

typedef __bf16 bf16_t;
typedef __bf16 bf16x4 __attribute__((ext_vector_type(4)));
typedef __bf16 bf16x8 __attribute__((ext_vector_type(8)));
typedef float  f32x4  __attribute__((ext_vector_type(4)));
typedef float  f32x16 __attribute__((ext_vector_type(16)));
typedef unsigned short u16x4 __attribute__((ext_vector_type(4)));
typedef unsigned int   u32x4 __attribute__((ext_vector_type(4)));

static constexpr int Bz = 2, S = 2048, E = 1024, H = 16, Dh = 64;
static constexpr int M  = Bz * S;   // 4096 tokens
static constexpr int N  = H * Dh;   // 1024
static constexpr int Kd = E;        // 1024

DEVI unsigned short f2bf(float f) {
  unsigned u = __builtin_bit_cast(unsigned, f);
  return (unsigned short)((u + 0x7fffu + ((u >> 16) & 1u)) >> 16);
}

DEVI void async_copy16(void* lds, const void* g) {
  __builtin_amdgcn_global_load_lds((__attribute__((address_space(1))) void*)(g),
                                   (__attribute__((address_space(3))) void*)(lds), 16, 0, 0);
}

DEVI void block_sync() { asm volatile("s_barrier" ::: "memory"); }
#define VMCNT4() asm volatile("s_waitcnt vmcnt(4)" ::: "memory")
#define VMCNT0() asm volatile("s_waitcnt vmcnt(0)" ::: "memory")
#define LGKM0()  asm volatile("s_waitcnt lgkmcnt(0)" ::: "memory")

// pack two f32 -> dword of two bf16 (RNE)
DEVI unsigned cvtpk(float lo, float hi) {
  unsigned r;
  asm("v_cvt_pk_bf16_f32 %0, %1, %2" : "=v"(r) : "v"(lo), "v"(hi));
  return r;
}
// swap x's lanes 32-63 with y's lanes 0-31
DEVI void swap32(unsigned& x, unsigned& y) {
  asm("v_permlane32_swap_b32 %0, %1" : "+v"(x), "+v"(y));
}

// ---------------- fused prep: convx | wtrans | rope table ----------------
__global__ void prep_kernel(const float* __restrict__ x, bf16_t* __restrict__ xb,
                            const float* __restrict__ Wq, const float* __restrict__ Wk,
                            const float* __restrict__ Wv, const float* __restrict__ Wo,
                            bf16_t* __restrict__ WtBase,
                            float* __restrict__ ropeC, float* __restrict__ ropeS) {
  __shared__ unsigned short tile[64][68];
  const int blk = blockIdx.x, tid = threadIdx.x;
  if (blk < 4096) {
    // x fp32 -> bf16
    int i = blk * 256 + tid;
    float4 v = ((const float4*)x)[i];
    u16x4 o = { f2bf(v.x), f2bf(v.y), f2bf(v.z), f2bf(v.w) };
    ((u16x4*)xb)[i] = o;
  } else if (blk < 5120) {
    // weight fp32 [K][N] -> bf16 [N][K]
    const int i = blk - 4096;
    const int z = i >> 8, rest = i & 255;
    const int n0 = (rest & 15) * 64, k0 = (rest >> 4) * 64;
    const float* W = (z == 0) ? Wq : (z == 1) ? Wk : (z == 2) ? Wv : Wo;
    unsigned short* T = (unsigned short*)(WtBase + (size_t)z * Kd * N);
    for (int e = tid; e < 1024; e += 256) {
      int r = e >> 4, c4 = (e & 15) * 4;
      float4 v = *(const float4*)(W + (size_t)(k0 + r) * N + n0 + c4);
      u16x4 o = { f2bf(v.x), f2bf(v.y), f2bf(v.z), f2bf(v.w) };
      *(u16x4*)&tile[r][c4] = o;
    }
    __syncthreads();
    for (int e = tid; e < 1024; e += 256) {
      int r = e >> 4, c4 = (e & 15) * 4;
      u16x4 o = { tile[c4][r], tile[c4 + 1][r], tile[c4 + 2][r], tile[c4 + 3][r] };
      *(u16x4*)&T[(size_t)(n0 + r) * Kd + k0 + c4] = o;
    }
  } else {
    int i = (blk - 5120) * 256 + tid;            // 65536 = 2048*32
    int pos = i >> 5, j = i & 31;
    float inv = exp2f(-(float)j * 0.41524101186092029f);   // log2(10000)/32
    float ang = (float)pos * inv;
    ropeC[i] = cosf(ang);
    ropeS[i] = sinf(ang);
  }
}

// bf16 [BH][S][D] -> tile-blocked V^T: [BH][S/32][D][32]
// (dense 4KB per 32-key tile -> attn V staging gets K-like 64B lane strides
//  instead of the old [D][S] layout's 4KB-stride 32-line gather)
__global__ void vtrans_kernel(const bf16_t* __restrict__ V, bf16_t* __restrict__ Vt) {
  __shared__ unsigned short tile[64][68];
  const int bh = blockIdx.y;
  const int s0 = blockIdx.x * 64;
  const unsigned short* Vp = (const unsigned short*)V + (size_t)bh * S * Dh;
  unsigned short* Tp = (unsigned short*)Vt + (size_t)bh * S * Dh;
  const int tid = threadIdx.x;
  for (int e = tid; e < 1024; e += 256) {
    int r = e >> 4, c4 = (e & 15) * 4;
    u16x4 v = *(const u16x4*)(Vp + (size_t)(s0 + r) * Dh + c4);
    *(u16x4*)&tile[r][c4] = v;
  }
  __syncthreads();
  for (int e = tid; e < 1024; e += 256) {
    int d = e >> 4, s4 = (e & 15) * 4;
    int t = (s0 + s4) >> 5, ks = (s0 + s4) & 31;      // s4 is 4-aligned, no 32-crossing
    u16x4 o = { tile[s4][d], tile[s4 + 1][d], tile[s4 + 2][d], tile[s4 + 3][d] };
    *(u16x4*)&Tp[((size_t)t * Dh + d) * 32 + ks] = o;
  }
}

// ---------------- GEMM core (128x128 tile, BK=32, global_load_lds) ----------------

DEVI void gemm_mainloop(const bf16_t* __restrict__ A, const bf16_t* __restrict__ Bt,
                        bf16_t* sA, bf16_t* sB, int m0, int n0, f32x4 (&acc)[4][4]) {
  const int tid  = threadIdx.x;
  const int lane = tid & 63;
  const int wid  = tid >> 6;
  const int l16  = lane & 15;
  const int quad = lane >> 4;
  const int wm = (wid >> 1) * 64;
  const int wn = (wid & 1) * 64;
  const int o0 = wid * 2048 + lane * 16;   // byte offset within 8KB tile
  const int o1 = o0 + 1024;
  const int r0 = o0 >> 6, c0 = o0 & 63;
  const int r1 = o1 >> 6, c1 = o1 & 63;
  const char* Ab = (const char*)A;
  const char* Bb = (const char*)Bt;
  char* sAc = (char*)sA;
  char* sBc = (char*)sB;

  for (int k0 = 0; k0 < Kd; k0 += 32) {
    __syncthreads();
    async_copy16(sAc + wid * 2048,        Ab + ((size_t)(m0 + r0) * Kd + k0) * 2 + c0);
    async_copy16(sAc + wid * 2048 + 1024, Ab + ((size_t)(m0 + r1) * Kd + k0) * 2 + c1);
    async_copy16(sBc + wid * 2048,        Bb + ((size_t)(n0 + r0) * Kd + k0) * 2 + c0);
    async_copy16(sBc + wid * 2048 + 1024, Bb + ((size_t)(n0 + r1) * Kd + k0) * 2 + c1);
    __syncthreads();
    bf16x8 af[4], bfv[4];
#pragma unroll
    for (int mi = 0; mi < 4; ++mi)
      af[mi] = *(const bf16x8*)(sA + (wm + mi * 16 + l16) * 32 + quad * 8);
#pragma unroll
    for (int ni = 0; ni < 4; ++ni)
      bfv[ni] = *(const bf16x8*)(sB + (wn + ni * 16 + l16) * 32 + quad * 8);
#pragma unroll
    for (int mi = 0; mi < 4; ++mi)
#pragma unroll
      for (int ni = 0; ni < 4; ++ni)
        acc[mi][ni] = __builtin_amdgcn_mfma_f32_16x16x32_bf16(af[mi], bfv[ni], acc[mi][ni], 0, 0, 0);
  }
}

// z = 0:Q(RoPE+scale) 1:K(RoPE) 2:V ; out layout [B,H,S,D] bf16
__global__ __launch_bounds__(256, 3) void gemm_qkv_kernel(
    const bf16_t* __restrict__ xb, const bf16_t* __restrict__ WtBase,
    const float* __restrict__ bq, const float* __restrict__ bk, const float* __restrict__ bv,
    bf16_t* __restrict__ outBase,
    const float* __restrict__ ropeC, const float* __restrict__ ropeS) {
  __shared__ bf16_t sA[4096], sB[4096];
  const int z = blockIdx.z;
  const bf16_t* Bt = WtBase + (size_t)z * Kd * N;
  const float* bias = (z == 0) ? bq : (z == 1) ? bk : bv;
  unsigned short* outp = (unsigned short*)(outBase + (size_t)z * M * N);
  const int n0 = blockIdx.x * 128, m0 = blockIdx.y * 128;
  f32x4 acc[4][4] = {};
  gemm_mainloop(xb, Bt, sA, sB, m0, n0, acc);

  const int tid = threadIdx.x, lane = tid & 63, wid = tid >> 6;
  const int l16 = lane & 15, quad = lane >> 4;
  const int wm = (wid >> 1) * 64, wn = (wid & 1) * 64;
  const int cbase = n0 + wn;          // 64-aligned -> one head per wave slab
  const int h = cbase >> 6;

  if (z < 2) {
    // Q gets 0.125 (=1/sqrt(D)) * log2(e) folded in so attention can use exp2
    const float qs = (z == 0) ? 0.18033688011112042f : 1.0f;
#pragma unroll
    for (int mi = 0; mi < 4; ++mi)
#pragma unroll
      for (int r = 0; r < 4; ++r) {
        int t = m0 + wm + mi * 16 + quad * 4 + r;
        int bb = t >> 11, s = t & (S - 1);
        size_t obase = ((size_t)(bb * H + h) * S + s) * Dh;
#pragma unroll
        for (int np = 0; np < 2; ++np) {
          int j = np * 16 + l16;                 // = d (low half), d-32 (high half)
          float cc = ropeC[s * 32 + j];
          float ss = ropeS[s * 32 + j];
          float xlo = acc[mi][np][r]     + bias[cbase + j];
          float xhi = acc[mi][np + 2][r] + bias[cbase + j + 32];
          outp[obase + j]      = f2bf((xlo * cc - xhi * ss) * qs);
          outp[obase + j + 32] = f2bf((xhi * cc + xlo * ss) * qs);
        }
      }
  } else {
#pragma unroll
    for (int mi = 0; mi < 4; ++mi)
#pragma unroll
      for (int r = 0; r < 4; ++r) {
        int t = m0 + wm + mi * 16 + quad * 4 + r;
        int bb = t >> 11, s = t & (S - 1);
        size_t obase = ((size_t)(bb * H + h) * S + s) * Dh;
#pragma unroll
        for (int ni = 0; ni < 4; ++ni) {
          int d = ni * 16 + l16;
          outp[obase + d] = f2bf(acc[mi][ni][r] + bias[cbase + d]);
        }
      }
  }
}

// output GEMM: 64(m) x 128(n) tiles -> 512 blocks (2/CU)
__global__ __launch_bounds__(256, 4) void gemm_o_kernel(
    const bf16_t* __restrict__ A, const bf16_t* __restrict__ Bt,
    const float* __restrict__ bias, float* __restrict__ out) {
  __shared__ bf16_t sA[2048], sB[4096];     // 4KB A (64x32), 8KB B (128x32)
  const int n0 = blockIdx.x * 128, m0 = blockIdx.y * 64;
  const int tid = threadIdx.x, lane = tid & 63, wid = tid >> 6;
  const int l16 = lane & 15, quad = lane >> 4;
  const int wm = (wid >> 1) * 32, wn = (wid & 1) * 64;
  const int rowoff = lane >> 2, col8 = (lane & 3) * 8;
  const char* Ab = (const char*)A;
  const char* Bb = (const char*)Bt;
  char* sAc = (char*)sA;
  char* sBc = (char*)sB;
  f32x4 acc[2][4] = {};

  for (int k0 = 0; k0 < Kd; k0 += 32) {
    __syncthreads();
    async_copy16(sAc + wid * 1024,
                 Ab + ((size_t)(m0 + wid * 16 + rowoff) * Kd + k0 + col8) * 2);
    async_copy16(sBc + (wid * 2) * 1024,
                 Bb + ((size_t)(n0 + wid * 32 + rowoff) * Kd + k0 + col8) * 2);
    async_copy16(sBc + (wid * 2 + 1) * 1024,
                 Bb + ((size_t)(n0 + wid * 32 + 16 + rowoff) * Kd + k0 + col8) * 2);
    __syncthreads();
    bf16x8 af[2], bfv[4];
#pragma unroll
    for (int mi = 0; mi < 2; ++mi)
      af[mi] = *(const bf16x8*)(sA + (wm + mi * 16 + l16) * 32 + quad * 8);
#pragma unroll
    for (int ni = 0; ni < 4; ++ni)
      bfv[ni] = *(const bf16x8*)(sB + (wn + ni * 16 + l16) * 32 + quad * 8);
#pragma unroll
    for (int mi = 0; mi < 2; ++mi)
#pragma unroll
      for (int ni = 0; ni < 4; ++ni)
        acc[mi][ni] = __builtin_amdgcn_mfma_f32_16x16x32_bf16(af[mi], bfv[ni], acc[mi][ni], 0, 0, 0);
  }
#pragma unroll
  for (int mi = 0; mi < 2; ++mi)
#pragma unroll
    for (int r = 0; r < 4; ++r) {
      int t = m0 + wm + mi * 16 + quad * 4 + r;
#pragma unroll
      for (int ni = 0; ni < 4; ++ni) {
        int c = n0 + wn + ni * 16 + l16;
        out[(size_t)t * N + c] = acc[mi][ni][r] + bias[c];
      }
    }
}

// ------- flash attention: 32x32 MFMA, 4-way split-K, 2 waves/group, 32-key tiles ---
// 512 blocks x 512 threads (8 waves = 4 groups x 2 waves). Block (p, bh) runs
// two phases: q-tile qt = 31-p then qt = p (64 q rows each; wave w2 owns 32).
// Within a phase the 2(qt+1) 32-key tiles split contiguously across 4 groups;
// slots/block = ceil((32-p)/2) + ceil((p+1)/2) = 17 for ALL blocks -> 512
// uniform blocks, 2 blocks/CU (67.5KB LDS), 16 waves/CU steady, no tail.
// V^T is tile-blocked [S/32][D][32] so BOTH K and V staging are dense 4KB
// regions with 64B lane strides (the old [D][S] V^T staging gathered 32 lines
// 4KB apart per instruction — the suspected per-slot serialization).
// Fixed-m softmax (scale*log2e folded into Q) -> split-K combine additive.
// QK^T swapped (K as A-operand) so P lands in D-layout; converted to the PV
// B-operand with v_cvt_pk_bf16_f32 + v_permlane32_swap_b32 (no LDS bounce).
// Double-buffered staging, counted vmcnt(4). Balanced combine via rotated LDS.
template <bool MASKED>
DEVI void attn32_phase(const bf16_t* __restrict__ Qp, const char* __restrict__ Kg,
                       const char* __restrict__ Vg, const int* __restrict__ mp,
                       unsigned short* __restrict__ cp, char* lds,
                       int b, int bh, int qt) {
  const int tid = threadIdx.x, lane = tid & 63, wid = tid >> 6;
  const int grp = wid >> 1, w2 = wid & 1;
  const int l32 = lane & 31, hi = lane >> 5;

  const int qw = qt * 64 + w2 * 32;        // wave's first q row
  const int qg = qw + l32;                 // this lane's q (as D-col)
  const int nk = 2 * (qt + 1);             // 32-key tiles in range
  const int qd = nk >> 2, rm = nk & 3;     // rm in {0,2}
  const int nG  = qd + ((grp < rm) ? 1 : 0);
  const int st0 = grp * qd + ((grp < rm) ? grp : rm);
  const int nMax = qd + (rm ? 1 : 0);      // uniform loop bound (same all groups)
  const int gk0 = st0 * 32;                // group's first key
  char* gB = lds + grp * 16384;            // per-group 16KB (2 x 8KB dbuf)

  // Q fragments (B-operand): B[k = hi*8+j][n = q = l32], d-chunk c
  bf16x8 qf[4];
#pragma unroll
  for (int c = 0; c < 4; ++c)
    qf[c] = *(const bf16x8*)(Qp + (size_t)(qw + l32) * Dh + c * 16 + hi * 8);
  // force Q-load waits here (pre-loop), keeping in-loop vmcnt accounting exact
  asm volatile("" :: "v"((float)qf[3][7]));

  // fragment-order staging: w2=0 stages the 4 K sections, w2=1 the 4 V sections
  // K section c: lane -> K[key=l32][d = c*16 + hi*8 ..+7]       (64B lane stride)
  // V section s=e*2+kc: lane -> V^T[d=e*32+l32][key = kc*16 + hi*8 ..+7]
  //   tile-blocked source: byte = d*64 + kc*32 + hi*16          (64B lane stride)
  int sLds[4], sOff[4];
#pragma unroll
  for (int i = 0; i < 4; ++i) {
    sLds[i] = (w2 * 4 + i) * 1024;
    if (w2 == 0) sOff[i] = (l32 * 64 + i * 16 + hi * 8) * 2;
    else         sOff[i] = ((i >> 1) * 32 + l32) * 64 + (i & 1) * 32 + hi * 16;
  }

  f32x16 cacc0 = {}, cacc1 = {};
  float lsum = 0.f;

  const char* gsrc = w2 ? Vg : Kg;         // both: 32-key tile = dense 4KB at key*128

  // prologue: stage tile 0 -> buffer 0
  if (nG > 0) {
    const char* bp = gsrc + (size_t)gk0 * 128;
#pragma unroll
    for (int i = 0; i < 4; ++i) async_copy16(gB + sLds[i], bp + sOff[i]);
  }

  for (int kt = 0; kt < nMax; ++kt) {
    const int cur = kt & 1;
    const int kb = gk0 + kt * 32;
    const bool act = kt < nG;
    unsigned long long dm = 0;
    if (act) {
      if (kt + 1 < nG) {
        const char* bp = gsrc + (size_t)(kb + 32) * 128;
        char* dst = gB + (cur ^ 1) * 8192;
#pragma unroll
        for (int i = 0; i < 4; ++i) async_copy16(dst + sLds[i], bp + sOff[i]);
        if (!MASKED) { VMCNT4(); }     // wait only for tile kt's 4 copies
      } else if (!MASKED) {
        VMCNT0();
      }
      if (MASKED) {
        int mk = mp[kb + l32];
        VMCNT0();
        dm = __ballot(mk == 0);
      }
    }
    block_sync();                       // tile kt visible to all waves

    if (act) {
      const bf16_t* sT = (const bf16_t*)(gB + cur * 8192);
      // S^T(32 keys x 32 q) = K . Q^T over d (4 chunks of 16)
      f32x16 st = {};
      __builtin_amdgcn_s_setprio(1);
#pragma unroll
      for (int c = 0; c < 4; ++c) {
        bf16x8 kf = *(const bf16x8*)(sT + c * 512 + lane * 8);
        st = __builtin_amdgcn_mfma_f32_32x32x16_bf16(kf, qf[c], st, 0, 0, 0);
      }
      __builtin_amdgcn_s_setprio(0);
      // D layout: col = q = l32, key-in-32 = (r&3) + 8*(r>>2) + 4*hi
      if (MASKED && dm) {
#pragma unroll
        for (int r = 0; r < 16; ++r)
          if ((dm >> ((r & 3) + 8 * (r >> 2) + 4 * hi)) & 1ull) st[r] = -1e30f;
      }
      if (kb + 31 > qw) {               // causal mask touches this tile
        const int kbase = kb + 4 * hi - qg;
#pragma unroll
        for (int r = 0; r < 16; ++r)
          if (kbase + (r & 3) + 8 * (r >> 2) > 0) st[r] = -1e30f;
      }
      // p = exp2(s) (fixed m); pack pairs to bf16 dwords
      unsigned P0[4], P1[4];
#pragma unroll
      for (int m = 0; m < 4; ++m) {
        float p0 = exp2f(st[4 * m + 0]), p1 = exp2f(st[4 * m + 1]);
        float p2 = exp2f(st[4 * m + 2]), p3 = exp2f(st[4 * m + 3]);
        lsum += (p0 + p1) + (p2 + p3);
        P0[m] = cvtpk(p0, p1);
        P1[m] = cvtpk(p2, p3);
      }
      // permlane32_swap -> PV B-operand frags (keys [0,16) and [16,32))
      swap32(P0[0], P0[1]); swap32(P1[0], P1[1]);
      swap32(P0[2], P0[3]); swap32(P1[2], P1[3]);
      u32x4 t0 = { P0[0], P1[0], P0[1], P1[1] };
      u32x4 t1 = { P0[2], P1[2], P0[3], P1[3] };
      const bf16x8 f0 = __builtin_bit_cast(bf16x8, t0);
      const bf16x8 f1 = __builtin_bit_cast(bf16x8, t1);
      // ctx^T += V^T . P^T
      __builtin_amdgcn_s_setprio(1);
      {
        bf16x8 v00 = *(const bf16x8*)(sT + 2048 + 0 * 512 + lane * 8);
        cacc0 = __builtin_amdgcn_mfma_f32_32x32x16_bf16(v00, f0, cacc0, 0, 0, 0);
        bf16x8 v01 = *(const bf16x8*)(sT + 2048 + 1 * 512 + lane * 8);
        cacc0 = __builtin_amdgcn_mfma_f32_32x32x16_bf16(v01, f1, cacc0, 0, 0, 0);
        bf16x8 v10 = *(const bf16x8*)(sT + 2048 + 2 * 512 + lane * 8);
        cacc1 = __builtin_amdgcn_mfma_f32_32x32x16_bf16(v10, f0, cacc1, 0, 0, 0);
        bf16x8 v11 = *(const bf16x8*)(sT + 2048 + 3 * 512 + lane * 8);
        cacc1 = __builtin_amdgcn_mfma_f32_32x32x16_bf16(v11, f1, cacc1, 0, 0, 0);
      }
      __builtin_amdgcn_s_setprio(0);
    }
    block_sync();                       // buf[cur] fully consumed
  }

  // ---- balanced 4-way combine: all 8 waves store rotated partials, then each
  // wave reduces 8 output rows. region: f32 reg[grp][row 64][d 64] (=64KB,
  // reuses staging space) + lsums f32[grp*2+hi][row 64] at +64KB.
  float* reg = (float*)lds;
  {
    const int row = w2 * 32 + l32;
    float* rb = reg + grp * 4096 + row * 64;
#pragma unroll
    for (int m = 0; m < 4; ++m) {
      f32x4 v = { cacc0[4 * m], cacc0[4 * m + 1], cacc0[4 * m + 2], cacc0[4 * m + 3] };
      *(f32x4*)(rb + ((8 * m + 4 * hi + 4 * row) & 63)) = v;
    }
#pragma unroll
    for (int m = 0; m < 4; ++m) {
      f32x4 v = { cacc1[4 * m], cacc1[4 * m + 1], cacc1[4 * m + 2], cacc1[4 * m + 3] };
      *(f32x4*)(rb + ((32 + 8 * m + 4 * hi + 4 * row) & 63)) = v;
    }
    reg[16384 + (grp * 2 + hi) * 64 + row] = lsum;
  }
  LGKM0();
  block_sync();
  {
    const int orow = wid * 8 + (lane & 7);   // each wave owns 8 rows
    const int d0 = (lane >> 3) * 8;          // 8 d-slices of 8
    f32x4 oa = {}, ob = {};
    float ls = 0.f;
#pragma unroll
    for (int g = 0; g < 4; ++g) {
      const float* rb = reg + g * 4096 + orow * 64;
      f32x4 va = *(const f32x4*)(rb + ((d0 + 4 * orow) & 63));
      f32x4 vb = *(const f32x4*)(rb + ((d0 + 4 + 4 * orow) & 63));
      oa += va; ob += vb;
      ls += reg[16384 + (g * 2 + 0) * 64 + orow] + reg[16384 + (g * 2 + 1) * 64 + orow];
    }
    const float inv = 1.0f / ls;
    const size_t base = ((size_t)(b * S + qt * 64 + orow)) * N + (size_t)(bh & 15) * Dh + d0;
    u16x4 o0 = { f2bf(oa[0] * inv), f2bf(oa[1] * inv), f2bf(oa[2] * inv), f2bf(oa[3] * inv) };
    u16x4 o1 = { f2bf(ob[0] * inv), f2bf(ob[1] * inv), f2bf(ob[2] * inv), f2bf(ob[3] * inv) };
    *(u16x4*)&cp[base] = o0;
    *(u16x4*)&cp[base + 4] = o1;
  }
  block_sync();    // combine region free before next phase's staging
}

__global__ __launch_bounds__(512, 4) void attn_kernel(
    const bf16_t* __restrict__ Q, const bf16_t* __restrict__ Kb,
    const bf16_t* __restrict__ Vt, const int* __restrict__ mask,
    bf16_t* __restrict__ ctx) {
  __shared__ f32x4 ldsbuf[4224];               // 67.5 KB (64KB stage/combine + lsums)

  const int idx = blockIdx.x;                  // 512 blocks
  const int p   = idx >> 5;                    // 0..15
  const int bh  = idx & 31;
  const int qtL = 31 - p, qtS = p;             // slots: ceil((32-p)/2)+ceil((p+1)/2)=17
  const int b   = bh >> 4;
  const int lane = threadIdx.x & 63;

  const bf16_t* Qp = Q + (size_t)bh * S * Dh;
  const char*   Kg = (const char*)(Kb + (size_t)bh * S * Dh);
  const char*   Vg = (const char*)(Vt + (size_t)bh * S * Dh);   // tile-blocked V^T
  const int*    mp = mask + b * S;

  // one pass over the mask row: all-alive -> fast path with zero in-loop
  // mask vmem (keeps the counted-vmcnt accounting exact)
  int dead = 0;
  const int4* mp4 = (const int4*)mp;
  for (int c = lane; c < S / 4; c += 64) {
    int4 m = mp4[c];
    dead |= (m.x == 0) | (m.y == 0) | (m.z == 0) | (m.w == 0);
  }
  const bool anydead = __ballot(dead != 0) != 0ull;

  unsigned short* cp = (unsigned short*)ctx;
  char* lds = (char*)ldsbuf;
  if (!anydead) {
    attn32_phase<false>(Qp, Kg, Vg, mp, cp, lds, b, bh, qtL);
    attn32_phase<false>(Qp, Kg, Vg, mp, cp, lds, b, bh, qtS);
  } else {
    attn32_phase<true>(Qp, Kg, Vg, mp, cp, lds, b, bh, qtL);
    attn32_phase<true>(Qp, Kg, Vg, mp, cp, lds, b, bh, qtS);
  }
}

// ---------------- launcher ----------------

extern "C" void kernel_launch(void* const* d_in, const int* in_sizes, int n_in,
                              void* d_out, int out_size, void* d_ws, size_t ws_size,
                              hipStream_t stream) {
  const float* x  = (const float*)d_in[0];
  const int*  msk = (const int*)d_in[1];
  const float* Wq = (const float*)d_in[2];
  const float* bq = (const float*)d_in[3];
  const float* Wk = (const float*)d_in[4];
  const float* bk = (const float*)d_in[5];
  const float* Wv = (const float*)d_in[6];
  const float* bv = (const float*)d_in[7];
  const float* Wo = (const float*)d_in[8];
  const float* bo = (const float*)d_in[9];
  float* out = (float*)d_out;
  (void)in_sizes; (void)n_in; (void)out_size; (void)ws_size;

  char* ws = (char*)d_ws;
  bf16_t* xb   = (bf16_t*)(ws);                      // 8 MB  [4096][1024]
  bf16_t* WT   = (bf16_t*)(ws + (8u  << 20));        // 8 MB  4 x [1024][1024] (N-major)
  bf16_t* qkv  = (bf16_t*)(ws + (16u << 20));        // 24 MB Q,K,V each [B,H,S,D]
  bf16_t* Qb   = qkv;
  bf16_t* Kbuf = qkv + (size_t)1 * M * N;
  bf16_t* Vb   = qkv + (size_t)2 * M * N;
  bf16_t* Vt   = xb;                                  // alias: xb dead after QKV GEMM
  bf16_t* ctx  = Vb;                                  // alias: V[B,H,S,D] dead after vtrans
  float* ropeC = (float*)(ws + (40u << 20));          // 256 KB
  float* ropeS = ropeC + (size_t)S * 32;              // 256 KB

  prep_kernel<<<5376, 256, 0, stream>>>(x, xb, Wq, Wk, Wv, Wo, WT, ropeC, ropeS);
  gemm_qkv_kernel<<<dim3(8, 32, 3), 256, 0, stream>>>(xb, WT, bq, bk, bv, qkv, ropeC, ropeS);
  vtrans_kernel<<<dim3(32, 32), 256, 0, stream>>>(Vb, Vt);
  attn_kernel<<<512, 512, 0, stream>>>(Qb, Kbuf, Vt, msk, ctx);
  gemm_o_kernel<<<dim3(8, 64), 256, 0, stream>>>(ctx, WT + (size_t)3 * Kd * N, bo, out);
}

// Round 7
// 193.973 us; speedup vs baseline: 1.1559x; 1.0228x over previous
//
#include <hip/hip_runtime.h>
#include <cstdint>
#include <cstddef>

#define DEVI __device__ __forceinline__

typedef __bf16 bf16_t;
typedef __bf16 bf16x4 __attribute__((ext_vector_type(4)));
typedef __bf16 bf16x8 __attribute__((ext_vector_type(8)));
typedef float  f32x4  __attribute__((ext_vector_type(4)));
typedef float  f32x16 __attribute__((ext_vector_type(16)));
typedef unsigned short u16x4 __attribute__((ext_vector_type(4)));
typedef unsigned int   u32x4 __attribute__((ext_vector_type(4)));

static constexpr int Bz = 2, S = 2048, E = 1024, H = 16, Dh = 64;
static constexpr int M  = Bz * S;   // 4096 tokens
static constexpr int N  = H * Dh;   // 1024
static constexpr int Kd = E;        // 1024

DEVI unsigned short f2bf(float f) {
  unsigned u = __builtin_bit_cast(unsigned, f);
  return (unsigned short)((u + 0x7fffu + ((u >> 16) & 1u)) >> 16);
}

DEVI void async_copy16(void* lds, const void* g) {
  __builtin_amdgcn_global_load_lds((__attribute__((address_space(1))) void*)(g),
                                   (__attribute__((address_space(3))) void*)(lds), 16, 0, 0);
}

DEVI void block_sync() { asm volatile("s_barrier" ::: "memory"); }
#define VMCNT4() asm volatile("s_waitcnt vmcnt(4)" ::: "memory")
#define VMCNT0() asm volatile("s_waitcnt vmcnt(0)" ::: "memory")
#define LGKM0()  asm volatile("s_waitcnt lgkmcnt(0)" ::: "memory")

// pack two f32 -> dword of two bf16 (RNE)
DEVI unsigned cvtpk(float lo, float hi) {
  unsigned r;
  asm("v_cvt_pk_bf16_f32 %0, %1, %2" : "=v"(r) : "v"(lo), "v"(hi));
  return r;
}
// swap x's lanes 32-63 with y's lanes 0-31
DEVI void swap32(unsigned& x, unsigned& y) {
  asm("v_permlane32_swap_b32 %0, %1" : "+v"(x), "+v"(y));
}

// ---------------- fused prep: convx | wtrans | rope table ----------------
__global__ void prep_kernel(const float* __restrict__ x, bf16_t* __restrict__ xb,
                            const float* __restrict__ Wq, const float* __restrict__ Wk,
                            const float* __restrict__ Wv, const float* __restrict__ Wo,
                            bf16_t* __restrict__ WtBase,
                            float* __restrict__ ropeC, float* __restrict__ ropeS) {
  __shared__ unsigned short tile[64][68];
  const int blk = blockIdx.x, tid = threadIdx.x;
  if (blk < 4096) {
    // x fp32 -> bf16
    int i = blk * 256 + tid;
    float4 v = ((const float4*)x)[i];
    u16x4 o = { f2bf(v.x), f2bf(v.y), f2bf(v.z), f2bf(v.w) };
    ((u16x4*)xb)[i] = o;
  } else if (blk < 5120) {
    // weight fp32 [K][N] -> bf16 [N][K]
    const int i = blk - 4096;
    const int z = i >> 8, rest = i & 255;
    const int n0 = (rest & 15) * 64, k0 = (rest >> 4) * 64;
    const float* W = (z == 0) ? Wq : (z == 1) ? Wk : (z == 2) ? Wv : Wo;
    unsigned short* T = (unsigned short*)(WtBase + (size_t)z * Kd * N);
    for (int e = tid; e < 1024; e += 256) {
      int r = e >> 4, c4 = (e & 15) * 4;
      float4 v = *(const float4*)(W + (size_t)(k0 + r) * N + n0 + c4);
      u16x4 o = { f2bf(v.x), f2bf(v.y), f2bf(v.z), f2bf(v.w) };
      *(u16x4*)&tile[r][c4] = o;
    }
    __syncthreads();
    for (int e = tid; e < 1024; e += 256) {
      int r = e >> 4, c4 = (e & 15) * 4;
      u16x4 o = { tile[c4][r], tile[c4 + 1][r], tile[c4 + 2][r], tile[c4 + 3][r] };
      *(u16x4*)&T[(size_t)(n0 + r) * Kd + k0 + c4] = o;
    }
  } else {
    int i = (blk - 5120) * 256 + tid;            // 65536 = 2048*32
    int pos = i >> 5, j = i & 31;
    float inv = exp2f(-(float)j * 0.41524101186092029f);   // log2(10000)/32
    float ang = (float)pos * inv;
    ropeC[i] = cosf(ang);
    ropeS[i] = sinf(ang);
  }
}

// bf16 [BH][S][D] -> tile-blocked V^T: [BH][S/32][D][32]  (dense 4KB per 32-key tile)
__global__ void vtrans_kernel(const bf16_t* __restrict__ V, bf16_t* __restrict__ Vt) {
  __shared__ unsigned short tile[64][68];
  const int bh = blockIdx.y;
  const int s0 = blockIdx.x * 64;
  const unsigned short* Vp = (const unsigned short*)V + (size_t)bh * S * Dh;
  unsigned short* Tp = (unsigned short*)Vt + (size_t)bh * S * Dh;
  const int tid = threadIdx.x;
  for (int e = tid; e < 1024; e += 256) {
    int r = e >> 4, c4 = (e & 15) * 4;
    u16x4 v = *(const u16x4*)(Vp + (size_t)(s0 + r) * Dh + c4);
    *(u16x4*)&tile[r][c4] = v;
  }
  __syncthreads();
  for (int e = tid; e < 1024; e += 256) {
    int d = e >> 4, s4 = (e & 15) * 4;
    int t = (s0 + s4) >> 5, ks = (s0 + s4) & 31;      // s4 is 4-aligned, no 32-crossing
    u16x4 o = { tile[s4][d], tile[s4 + 1][d], tile[s4 + 2][d], tile[s4 + 3][d] };
    *(u16x4*)&Tp[((size_t)t * Dh + d) * 32 + ks] = o;
  }
}

// ---------------- GEMM core (128x128 tile, BK=32, global_load_lds) ----------------

DEVI void gemm_mainloop(const bf16_t* __restrict__ A, const bf16_t* __restrict__ Bt,
                        bf16_t* sA, bf16_t* sB, int m0, int n0, f32x4 (&acc)[4][4]) {
  const int tid  = threadIdx.x;
  const int lane = tid & 63;
  const int wid  = tid >> 6;
  const int l16  = lane & 15;
  const int quad = lane >> 4;
  const int wm = (wid >> 1) * 64;
  const int wn = (wid & 1) * 64;
  const int o0 = wid * 2048 + lane * 16;   // byte offset within 8KB tile
  const int o1 = o0 + 1024;
  const int r0 = o0 >> 6, c0 = o0 & 63;
  const int r1 = o1 >> 6, c1 = o1 & 63;
  const char* Ab = (const char*)A;
  const char* Bb = (const char*)Bt;
  char* sAc = (char*)sA;
  char* sBc = (char*)sB;

  for (int k0 = 0; k0 < Kd; k0 += 32) {
    __syncthreads();
    async_copy16(sAc + wid * 2048,        Ab + ((size_t)(m0 + r0) * Kd + k0) * 2 + c0);
    async_copy16(sAc + wid * 2048 + 1024, Ab + ((size_t)(m0 + r1) * Kd + k0) * 2 + c1);
    async_copy16(sBc + wid * 2048,        Bb + ((size_t)(n0 + r0) * Kd + k0) * 2 + c0);
    async_copy16(sBc + wid * 2048 + 1024, Bb + ((size_t)(n0 + r1) * Kd + k0) * 2 + c1);
    __syncthreads();
    bf16x8 af[4], bfv[4];
#pragma unroll
    for (int mi = 0; mi < 4; ++mi)
      af[mi] = *(const bf16x8*)(sA + (wm + mi * 16 + l16) * 32 + quad * 8);
#pragma unroll
    for (int ni = 0; ni < 4; ++ni)
      bfv[ni] = *(const bf16x8*)(sB + (wn + ni * 16 + l16) * 32 + quad * 8);
#pragma unroll
    for (int mi = 0; mi < 4; ++mi)
#pragma unroll
      for (int ni = 0; ni < 4; ++ni)
        acc[mi][ni] = __builtin_amdgcn_mfma_f32_16x16x32_bf16(af[mi], bfv[ni], acc[mi][ni], 0, 0, 0);
  }
}

// z = 0:Q(RoPE+scale) 1:K(RoPE) 2:V ; out layout [B,H,S,D] bf16
__global__ __launch_bounds__(256, 3) void gemm_qkv_kernel(
    const bf16_t* __restrict__ xb, const bf16_t* __restrict__ WtBase,
    const float* __restrict__ bq, const float* __restrict__ bk, const float* __restrict__ bv,
    bf16_t* __restrict__ outBase,
    const float* __restrict__ ropeC, const float* __restrict__ ropeS) {
  __shared__ bf16_t sA[4096], sB[4096];
  const int z = blockIdx.z;
  const bf16_t* Bt = WtBase + (size_t)z * Kd * N;
  const float* bias = (z == 0) ? bq : (z == 1) ? bk : bv;
  unsigned short* outp = (unsigned short*)(outBase + (size_t)z * M * N);
  const int n0 = blockIdx.x * 128, m0 = blockIdx.y * 128;
  f32x4 acc[4][4] = {};
  gemm_mainloop(xb, Bt, sA, sB, m0, n0, acc);

  const int tid = threadIdx.x, lane = tid & 63, wid = tid >> 6;
  const int l16 = lane & 15, quad = lane >> 4;
  const int wm = (wid >> 1) * 64, wn = (wid & 1) * 64;
  const int cbase = n0 + wn;          // 64-aligned -> one head per wave slab
  const int h = cbase >> 6;

  if (z < 2) {
    // Q gets 0.125 (=1/sqrt(D)) * log2(e) folded in so attention can use exp2
    const float qs = (z == 0) ? 0.18033688011112042f : 1.0f;
#pragma unroll
    for (int mi = 0; mi < 4; ++mi)
#pragma unroll
      for (int r = 0; r < 4; ++r) {
        int t = m0 + wm + mi * 16 + quad * 4 + r;
        int bb = t >> 11, s = t & (S - 1);
        size_t obase = ((size_t)(bb * H + h) * S + s) * Dh;
#pragma unroll
        for (int np = 0; np < 2; ++np) {
          int j = np * 16 + l16;                 // = d (low half), d-32 (high half)
          float cc = ropeC[s * 32 + j];
          float ss = ropeS[s * 32 + j];
          float xlo = acc[mi][np][r]     + bias[cbase + j];
          float xhi = acc[mi][np + 2][r] + bias[cbase + j + 32];
          outp[obase + j]      = f2bf((xlo * cc - xhi * ss) * qs);
          outp[obase + j + 32] = f2bf((xhi * cc + xlo * ss) * qs);
        }
      }
  } else {
#pragma unroll
    for (int mi = 0; mi < 4; ++mi)
#pragma unroll
      for (int r = 0; r < 4; ++r) {
        int t = m0 + wm + mi * 16 + quad * 4 + r;
        int bb = t >> 11, s = t & (S - 1);
        size_t obase = ((size_t)(bb * H + h) * S + s) * Dh;
#pragma unroll
        for (int ni = 0; ni < 4; ++ni) {
          int d = ni * 16 + l16;
          outp[obase + d] = f2bf(acc[mi][ni][r] + bias[cbase + d]);
        }
      }
  }
}

// output GEMM: 64(m) x 128(n) tiles -> 512 blocks (2/CU)
__global__ __launch_bounds__(256, 4) void gemm_o_kernel(
    const bf16_t* __restrict__ A, const bf16_t* __restrict__ Bt,
    const float* __restrict__ bias, float* __restrict__ out) {
  __shared__ bf16_t sA[2048], sB[4096];     // 4KB A (64x32), 8KB B (128x32)
  const int n0 = blockIdx.x * 128, m0 = blockIdx.y * 64;
  const int tid = threadIdx.x, lane = tid & 63, wid = tid >> 6;
  const int l16 = lane & 15, quad = lane >> 4;
  const int wm = (wid >> 1) * 32, wn = (wid & 1) * 64;
  const int rowoff = lane >> 2, col8 = (lane & 3) * 8;
  const char* Ab = (const char*)A;
  const char* Bb = (const char*)Bt;
  char* sAc = (char*)sA;
  char* sBc = (char*)sB;
  f32x4 acc[2][4] = {};

  for (int k0 = 0; k0 < Kd; k0 += 32) {
    __syncthreads();
    async_copy16(sAc + wid * 1024,
                 Ab + ((size_t)(m0 + wid * 16 + rowoff) * Kd + k0 + col8) * 2);
    async_copy16(sBc + (wid * 2) * 1024,
                 Bb + ((size_t)(n0 + wid * 32 + rowoff) * Kd + k0 + col8) * 2);
    async_copy16(sBc + (wid * 2 + 1) * 1024,
                 Bb + ((size_t)(n0 + wid * 32 + 16 + rowoff) * Kd + k0 + col8) * 2);
    __syncthreads();
    bf16x8 af[2], bfv[4];
#pragma unroll
    for (int mi = 0; mi < 2; ++mi)
      af[mi] = *(const bf16x8*)(sA + (wm + mi * 16 + l16) * 32 + quad * 8);
#pragma unroll
    for (int ni = 0; ni < 4; ++ni)
      bfv[ni] = *(const bf16x8*)(sB + (wn + ni * 16 + l16) * 32 + quad * 8);
#pragma unroll
    for (int mi = 0; mi < 2; ++mi)
#pragma unroll
      for (int ni = 0; ni < 4; ++ni)
        acc[mi][ni] = __builtin_amdgcn_mfma_f32_16x16x32_bf16(af[mi], bfv[ni], acc[mi][ni], 0, 0, 0);
  }
#pragma unroll
  for (int mi = 0; mi < 2; ++mi)
#pragma unroll
    for (int r = 0; r < 4; ++r) {
      int t = m0 + wm + mi * 16 + quad * 4 + r;
#pragma unroll
      for (int ni = 0; ni < 4; ++ni) {
        int c = n0 + wn + ni * 16 + l16;
        out[(size_t)t * N + c] = acc[mi][ni][r] + bias[c];
      }
    }
}

// ------- flash attention: 32x32 MFMA, 128-row q-tiles, 2-way split-K ----------
// 512 blocks x 512 threads (8 waves = 4 q-position waves x 2 split-K groups).
// Block handles q-tile j (128 rows; wave w4 owns rows j*128 + w4*32 ..+32).
// Keys [0, (j+1)*128) split contiguously across the 2 groups -> (j+1) slots of
// 64 keys per group; each staged tile feeds all 4 q-waves of the group ->
// staged volume HALVED vs the 64-row structure (the measured per-CU staging
// rate ~9B/cyc was the binding constraint; slot-instances/CU drop 34 -> 17).
// Index map: t=idx>>5, j = t<8 ? 15-t : t-8 -> co-resident pairs {c, c+256}
// sum to 17 slots; bh stays in idx&31 for XCD L2 locality.
// Per slot: stage 16KB (4 copies/wave, counted vmcnt(4), dbuf), 2 x 32-key
// sub-tiles: QK^T swapped (K as A-op) -> P in D-layout -> cvt_pk + permlane32
// to PV B-op in-register; V via tile-blocked dense V^T. Fixed-m softmax
// (scale*log2e in Q) -> 2-way combine additive (grp1 -> rotated LDS, grp0
// reduces + writes).
template <bool MASKED>
DEVI void attn32_tile(const bf16_t* __restrict__ Qp, const char* __restrict__ Kg,
                      const char* __restrict__ Vg, const int* __restrict__ mp,
                      unsigned short* __restrict__ cp, char* lds,
                      int b, int bh, int j) {
  const int tid = threadIdx.x, lane = tid & 63, wid = tid >> 6;
  const int grp = wid >> 2, w4 = wid & 3;
  const int l32 = lane & 31, hi = lane >> 5;

  const int qw = j * 128 + w4 * 32;        // wave's first q row
  const int qg = qw + l32;                 // this lane's q (as D-col)
  const int nIt = j + 1;                   // 64-key tiles per group
  const int gk0 = grp * nIt * 64;          // group's first key
  char* gB = lds + grp * 32768;            // per-group 32KB (2 x 16KB dbuf)

  // Q fragments (B-operand): B[k = hi*8+jj][n = q = l32], d-chunk c
  bf16x8 qf[4];
#pragma unroll
  for (int c = 0; c < 4; ++c)
    qf[c] = *(const bf16x8*)(Qp + (size_t)(qw + l32) * Dh + c * 16 + hi * 8);
  // force Q-load waits here (pre-loop), keeping in-loop vmcnt accounting exact
  asm volatile("" :: "v"((float)qf[3][7]));

  // 16 x 1KB sections per 64-key tile: s<8 K (a=s>>2 key-sub, c=s&3 d-chunk),
  // s>=8 V (t=s-8: a=t>>2 key-sub, v=t&3). Wave w4 stages sections w4*4..+3.
  // K src:  (a*32 + l32)*128 + c*32 + hi*16            (64B lane stride, dense)
  // V src (tile-blocked [key32][d64][key32-inner]):
  //         a*4096 + ((v>>1)*32 + l32)*64 + (v&1)*32 + hi*16
  int sLds[4], sOff[4];
#pragma unroll
  for (int i = 0; i < 4; ++i) {
    const int s = w4 * 4 + i;
    sLds[i] = s * 1024;
    if (s < 8) {
      const int a = s >> 2, c = s & 3;
      sOff[i] = (a * 32 + l32) * 128 + c * 32 + hi * 16;
    } else {
      const int t = s - 8, a = t >> 2, v = t & 3;
      sOff[i] = a * 4096 + ((v >> 1) * 32 + l32) * 64 + (v & 1) * 32 + hi * 16;
    }
  }
  const char* gsrc = (w4 < 2) ? Kg : Vg;   // both: 128B per key, dense 4KB/32keys

  f32x16 cacc0 = {}, cacc1 = {};
  float lsum = 0.f;

  // prologue: stage tile 0 -> buffer 0
  {
    const char* bp = gsrc + (size_t)gk0 * 128;
#pragma unroll
    for (int i = 0; i < 4; ++i) async_copy16(gB + sLds[i], bp + sOff[i]);
  }

  for (int kt = 0; kt < nIt; ++kt) {
    const int cur = kt & 1;
    const int kb = gk0 + kt * 64;
    unsigned long long dm = 0;
    if (kt + 1 < nIt) {
      const char* bp = gsrc + (size_t)(kb + 64) * 128;
      char* dst = gB + (cur ^ 1) * 16384;
#pragma unroll
      for (int i = 0; i < 4; ++i) async_copy16(dst + sLds[i], bp + sOff[i]);
      if (!MASKED) { VMCNT4(); }     // wait only for tile kt's 4 copies
    } else if (!MASKED) {
      VMCNT0();
    }
    if (MASKED) {
      int mk = mp[kb + lane];        // 64 keys, one per lane
      VMCNT0();
      dm = __ballot(mk == 0);
    }
    block_sync();                     // tile kt visible to all waves

    const bf16_t* sT = (const bf16_t*)(gB + cur * 16384);
#pragma unroll
    for (int a = 0; a < 2; ++a) {
      // S^T(32 keys x 32 q) = K . Q^T over d (4 chunks of 16)
      f32x16 st = {};
      __builtin_amdgcn_s_setprio(1);
#pragma unroll
      for (int c = 0; c < 4; ++c) {
        bf16x8 kf = *(const bf16x8*)(sT + a * 2048 + c * 512 + lane * 8);
        st = __builtin_amdgcn_mfma_f32_32x32x16_bf16(kf, qf[c], st, 0, 0, 0);
      }
      __builtin_amdgcn_s_setprio(0);
      // D layout: col = q = l32, key-in-32 = (r&3) + 8*(r>>2) + 4*hi
      if (MASKED && dm) {
#pragma unroll
        for (int r = 0; r < 16; ++r)
          if ((dm >> (a * 32 + (r & 3) + 8 * (r >> 2) + 4 * hi)) & 1ull) st[r] = -1e30f;
      }
      const int kba = kb + a * 32;
      if (kba + 31 > qw) {            // causal mask touches this sub-tile
        const int kbase = kba + 4 * hi - qg;
#pragma unroll
        for (int r = 0; r < 16; ++r)
          if (kbase + (r & 3) + 8 * (r >> 2) > 0) st[r] = -1e30f;
      }
      // p = exp2(s) (fixed m); pack pairs to bf16 dwords
      unsigned P0[4], P1[4];
#pragma unroll
      for (int m = 0; m < 4; ++m) {
        float p0 = exp2f(st[4 * m + 0]), p1 = exp2f(st[4 * m + 1]);
        float p2 = exp2f(st[4 * m + 2]), p3 = exp2f(st[4 * m + 3]);
        lsum += (p0 + p1) + (p2 + p3);
        P0[m] = cvtpk(p0, p1);
        P1[m] = cvtpk(p2, p3);
      }
      // permlane32_swap -> PV B-operand frags (keys [0,16) and [16,32) of sub)
      swap32(P0[0], P0[1]); swap32(P1[0], P1[1]);
      swap32(P0[2], P0[3]); swap32(P1[2], P1[3]);
      u32x4 t0 = { P0[0], P1[0], P0[1], P1[1] };
      u32x4 t1 = { P0[2], P1[2], P0[3], P1[3] };
      const bf16x8 f0 = __builtin_bit_cast(bf16x8, t0);
      const bf16x8 f1 = __builtin_bit_cast(bf16x8, t1);
      // ctx^T += V^T . P^T   (V sections at +8KB, sub a at +a*4KB)
      __builtin_amdgcn_s_setprio(1);
      {
        bf16x8 v00 = *(const bf16x8*)(sT + 4096 + a * 2048 + 0 * 512 + lane * 8);
        cacc0 = __builtin_amdgcn_mfma_f32_32x32x16_bf16(v00, f0, cacc0, 0, 0, 0);
        bf16x8 v01 = *(const bf16x8*)(sT + 4096 + a * 2048 + 1 * 512 + lane * 8);
        cacc0 = __builtin_amdgcn_mfma_f32_32x32x16_bf16(v01, f1, cacc0, 0, 0, 0);
        bf16x8 v10 = *(const bf16x8*)(sT + 4096 + a * 2048 + 2 * 512 + lane * 8);
        cacc1 = __builtin_amdgcn_mfma_f32_32x32x16_bf16(v10, f0, cacc1, 0, 0, 0);
        bf16x8 v11 = *(const bf16x8*)(sT + 4096 + a * 2048 + 3 * 512 + lane * 8);
        cacc1 = __builtin_amdgcn_mfma_f32_32x32x16_bf16(v11, f1, cacc1, 0, 0, 0);
      }
      __builtin_amdgcn_s_setprio(0);
    }
    block_sync();                     // buf[cur] fully consumed
  }

  // ---- 2-way split-K combine: grp1 stores rotated partials, grp0 reduces ----
  // region per w4: f32 [q 32][d 64] (8KB) at reg + w4*2048; rotation
  // (d + 4q)&63 -> bank-spread f32x4. lsum at float ofs 8192 + w4*32 + l32.
  lsum += __shfl_xor(lsum, 32);       // fold key-halves: all lanes = full lsum(q)
  float* reg = (float*)lds;
  if (grp == 1) {
    float* rb = reg + w4 * 2048 + l32 * 64;
#pragma unroll
    for (int m = 0; m < 4; ++m) {
      f32x4 v = { cacc0[4 * m], cacc0[4 * m + 1], cacc0[4 * m + 2], cacc0[4 * m + 3] };
      *(f32x4*)(rb + ((8 * m + 4 * hi + 4 * l32) & 63)) = v;
    }
#pragma unroll
    for (int m = 0; m < 4; ++m) {
      f32x4 v = { cacc1[4 * m], cacc1[4 * m + 1], cacc1[4 * m + 2], cacc1[4 * m + 3] };
      *(f32x4*)(rb + ((32 + 8 * m + 4 * hi + 4 * l32) & 63)) = v;
    }
    reg[8192 + w4 * 32 + l32] = lsum;
  }
  LGKM0();
  block_sync();
  if (grp == 0) {
    const float* rb = reg + w4 * 2048 + l32 * 64;
#pragma unroll
    for (int m = 0; m < 4; ++m) {
      f32x4 v = *(const f32x4*)(rb + ((8 * m + 4 * hi + 4 * l32) & 63));
      cacc0[4 * m] += v[0]; cacc0[4 * m + 1] += v[1];
      cacc0[4 * m + 2] += v[2]; cacc0[4 * m + 3] += v[3];
    }
#pragma unroll
    for (int m = 0; m < 4; ++m) {
      f32x4 v = *(const f32x4*)(rb + ((32 + 8 * m + 4 * hi + 4 * l32) & 63));
      cacc1[4 * m] += v[0]; cacc1[4 * m + 1] += v[1];
      cacc1[4 * m + 2] += v[2]; cacc1[4 * m + 3] += v[3];
    }
    const float inv = 1.0f / (lsum + reg[8192 + w4 * 32 + l32]);
    const size_t base = ((size_t)(b * S + qw + l32)) * N + (size_t)(bh & 15) * Dh;
#pragma unroll
    for (int m = 0; m < 4; ++m) {
      const int d0 = m * 8 + 4 * hi;   // d = (r&3) + 8m + 4hi
      u16x4 o0 = { f2bf(cacc0[4 * m + 0] * inv), f2bf(cacc0[4 * m + 1] * inv),
                   f2bf(cacc0[4 * m + 2] * inv), f2bf(cacc0[4 * m + 3] * inv) };
      *(u16x4*)&cp[base + d0] = o0;
      u16x4 o1 = { f2bf(cacc1[4 * m + 0] * inv), f2bf(cacc1[4 * m + 1] * inv),
                   f2bf(cacc1[4 * m + 2] * inv), f2bf(cacc1[4 * m + 3] * inv) };
      *(u16x4*)&cp[base + 32 + d0] = o1;
    }
  }
}

__global__ __launch_bounds__(512, 4) void attn_kernel(
    const bf16_t* __restrict__ Q, const bf16_t* __restrict__ Kb,
    const bf16_t* __restrict__ Vt, const int* __restrict__ mask,
    bf16_t* __restrict__ ctx) {
  __shared__ f32x4 ldsbuf[4096];               // 64 KB (staging; combine overlaps)

  const int idx = blockIdx.x;                  // 512 blocks
  const int t   = idx >> 5;
  const int j   = (t < 8) ? (15 - t) : (t - 8);  // pairs {c,c+256} sum to 17 slots
  const int bh  = idx & 31;                      // low bits -> XCD locality
  const int b   = bh >> 4;
  const int lane = threadIdx.x & 63;

  const bf16_t* Qp = Q + (size_t)bh * S * Dh;
  const char*   Kg = (const char*)(Kb + (size_t)bh * S * Dh);
  const char*   Vg = (const char*)(Vt + (size_t)bh * S * Dh);   // tile-blocked V^T
  const int*    mp = mask + b * S;

  // one pass over the mask row: all-alive -> fast path with zero in-loop
  // mask vmem (keeps the counted-vmcnt accounting exact)
  int dead = 0;
  const int4* mp4 = (const int4*)mp;
  for (int c = lane; c < S / 4; c += 64) {
    int4 m = mp4[c];
    dead |= (m.x == 0) | (m.y == 0) | (m.z == 0) | (m.w == 0);
  }
  const bool anydead = __ballot(dead != 0) != 0ull;

  unsigned short* cp = (unsigned short*)ctx;
  char* lds = (char*)ldsbuf;
  if (!anydead)
    attn32_tile<false>(Qp, Kg, Vg, mp, cp, lds, b, bh, j);
  else
    attn32_tile<true>(Qp, Kg, Vg, mp, cp, lds, b, bh, j);
}

// ---------------- launcher ----------------

extern "C" void kernel_launch(void* const* d_in, const int* in_sizes, int n_in,
                              void* d_out, int out_size, void* d_ws, size_t ws_size,
                              hipStream_t stream) {
  const float* x  = (const float*)d_in[0];
  const int*  msk = (const int*)d_in[1];
  const float* Wq = (const float*)d_in[2];
  const float* bq = (const float*)d_in[3];
  const float* Wk = (const float*)d_in[4];
  const float* bk = (const float*)d_in[5];
  const float* Wv = (const float*)d_in[6];
  const float* bv = (const float*)d_in[7];
  const float* Wo = (const float*)d_in[8];
  const float* bo = (const float*)d_in[9];
  float* out = (float*)d_out;
  (void)in_sizes; (void)n_in; (void)out_size; (void)ws_size;

  char* ws = (char*)d_ws;
  bf16_t* xb   = (bf16_t*)(ws);                      // 8 MB  [4096][1024]
  bf16_t* WT   = (bf16_t*)(ws + (8u  << 20));        // 8 MB  4 x [1024][1024] (N-major)
  bf16_t* qkv  = (bf16_t*)(ws + (16u << 20));        // 24 MB Q,K,V each [B,H,S,D]
  bf16_t* Qb   = qkv;
  bf16_t* Kbuf = qkv + (size_t)1 * M * N;
  bf16_t* Vb   = qkv + (size_t)2 * M * N;
  bf16_t* Vt   = xb;                                  // alias: xb dead after QKV GEMM
  bf16_t* ctx  = Vb;                                  // alias: V[B,H,S,D] dead after vtrans
  float* ropeC = (float*)(ws + (40u << 20));          // 256 KB
  float* ropeS = ropeC + (size_t)S * 32;              // 256 KB

  prep_kernel<<<5376, 256, 0, stream>>>(x, xb, Wq, Wk, Wv, Wo, WT, ropeC, ropeS);
  gemm_qkv_kernel<<<dim3(8, 32, 3), 256, 0, stream>>>(xb, WT, bq, bk, bv, qkv, ropeC, ropeS);
  vtrans_kernel<<<dim3(32, 32), 256, 0, stream>>>(Vb, Vt);
  attn_kernel<<<512, 512, 0, stream>>>(Qb, Kbuf, Vt, msk, ctx);
  gemm_o_kernel<<<dim3(8, 64), 256, 0, stream>>>(ctx, WT + (size_t)3 * Kd * N, bo, out);
}